// Round 2
// baseline (1187.730 us; speedup 1.0000x reference)
//
#include <hip/hip_runtime.h>
#include <math.h>

#define NG 76800
#define EG 307200
#define NL 38400
#define EL 153600
#define NB 64
#define NH 8

typedef __attribute__((ext_vector_type(8))) short bf16x8;
typedef __attribute__((ext_vector_type(4))) float f32x4;
typedef unsigned short u16;

__device__ __forceinline__ float sigmoidf(float x) { return 1.f / (1.f + expf(-x)); }
__device__ __forceinline__ u16 f2bf(float x) {
    unsigned u = __float_as_uint(x);
    return (u16)((u + 0x7FFFu + ((u >> 16) & 1u)) >> 16);
}
__device__ __forceinline__ float bf2f(u16 v) { return __uint_as_float(((unsigned)v) << 16); }

// ---------------- fp32 -> padded bf16 [M x Kpad] ----------------
__global__ __launch_bounds__(256) void convert_pad_kernel(const float* __restrict__ src,
                                                          u16* __restrict__ dst,
                                                          int M, int K, int Kpad) {
    int i = blockIdx.x * 256 + threadIdx.x;
    if (i >= M * Kpad) return;
    int m = i / Kpad, k = i - m * Kpad;
    dst[i] = (k < K) ? f2bf(src[(size_t)m * K + k]) : (u16)0;
}

// ---------------- W[K x Nfull] -> bf16 Wt[Nalloc x Kpad] (zero padded) ----------------
__global__ __launch_bounds__(256) void wtrans_kernel(const float* __restrict__ W, int ldw,
                                                     u16* __restrict__ dst,
                                                     int K, int N, int Nalloc, int Kpad) {
    int i = blockIdx.x * 256 + threadIdx.x;
    if (i >= Nalloc * Kpad) return;
    int n = i / Kpad, k = i - n * Kpad;
    dst[i] = (n < N && k < K) ? f2bf(W[(size_t)k * ldw + n]) : (u16)0;
}

// ---------------- head-padded transform: FE 36->40, 8 heads, R=320 rows ----------------
__global__ __launch_bounds__(256) void wtrans_hp_kernel(const float* __restrict__ W, int ldw,
                                                        u16* __restrict__ dst,
                                                        int K, int Kpad) {
    int i = blockIdx.x * 256 + threadIdx.x;
    if (i >= 320 * Kpad) return;
    int n = i / Kpad, k = i - n * Kpad;
    int hh = n / 40, f = n - hh * 40;
    float v = (k < K && f < 36) ? W[(size_t)k * ldw + hh * 36 + f] : 0.f;
    dst[i] = f2bf(v);
}

// ---------------- meta: padded attn1 + concat biases ----------------
__global__ __launch_bounds__(256) void meta_kernel(const float* __restrict__ attn1,
                                                   const float* __restrict__ bias1,
                                                   const float* __restrict__ b2a,
                                                   const float* __restrict__ b2b,
                                                   float* __restrict__ attn_p1,
                                                   float* __restrict__ bias_cat1,
                                                   float* __restrict__ bias_cat2a,
                                                   float* __restrict__ bias_cat2b) {
    int i = blockIdx.x * 256 + threadIdx.x;
    if (i < 320) {
        int hh = i / 40, f = i - hh * 40;
        attn_p1[i] = (f < 36) ? attn1[hh * 36 + f] : 0.f;
    } else if (i < 960) {
        int j = i - 320;
        float v = 0.f;
        if (j < 320) {
            int hh = j / 40, f = j - hh * 40;
            v = (f < 36) ? bias1[hh * 36 + f] : 0.f;
        }
        bias_cat1[j] = v;
    } else if (i < 1600) {
        int j = i - 960;
        bias_cat2a[j] = (j < 320) ? b2a[j] : 0.f;
    } else if (i < 2240) {
        int j = i - 1600;
        bias_cat2b[j] = (j < 320) ? b2b[j] : 0.f;
    }
}

// ---------------- LDS-free bf16 MFMA GEMM, packed dwordx2 epilogue ----------------
// Epilogue: quad-transpose via shfl_xor(1)/shfl_xor(2) so each lane stores 4
// consecutive bf16 cols of one row as a single 8B store (4 stores/lane vs 16
// scalar u16 stores). Requires Ncols % 4 == 0 and (Ncols*2) % 8 == 0 (all
// callers: 320/640/736).
template <int KPAD>
__global__ __launch_bounds__(256) void gemm_bf_kernel(const u16* __restrict__ A,
                                                      const u16* __restrict__ Wt,
                                                      const float* __restrict__ bias,
                                                      u16* __restrict__ C, int Ncols) {
    const int m0 = blockIdx.x * 64;
    const int n0 = blockIdx.y * 64;
    const int wv = threadIdx.x >> 6;
    const int lane = threadIdx.x & 63;
    const int q = lane >> 4;
    const int mr = lane & 15;

    const u16* Arow = A + (size_t)(m0 + wv * 16 + mr) * KPAD;
    f32x4 acc[4];
#pragma unroll
    for (int t = 0; t < 4; ++t) acc[t] = (f32x4){0.f, 0.f, 0.f, 0.f};

#pragma unroll
    for (int k0 = 0; k0 < KPAD; k0 += 32) {
        bf16x8 af = *(const bf16x8*)(Arow + k0 + q * 8);
#pragma unroll
        for (int t = 0; t < 4; ++t) {
            bf16x8 bv = *(const bf16x8*)(Wt + (size_t)(n0 + t * 16 + mr) * KPAD + k0 + q * 8);
            acc[t] = __builtin_amdgcn_mfma_f32_16x16x32_bf16(af, bv, acc[t], 0, 0, 0);
        }
    }

    const int r_own = mr & 3;
#pragma unroll
    for (int t = 0; t < 4; ++t) {
        const int colme = n0 + t * 16 + mr;
        const float bb = bias ? bias[colme] : 0.f;
        unsigned h[4];
#pragma unroll
        for (int r = 0; r < 4; ++r) h[r] = (unsigned)f2bf(acc[t][r] + bb);
        unsigned lo = 0, hi = 0;
#pragma unroll
        for (int r = 0; r < 4; ++r) {
            unsigned p = __shfl_xor(h[r], 1, 64);
            unsigned pk = (mr & 1) ? (p | (h[r] << 16)) : (h[r] | (p << 16));
            unsigned p2 = __shfl_xor(pk, 2, 64);
            unsigned l = (mr & 2) ? p2 : pk;
            unsigned g = (mr & 2) ? pk : p2;
            lo = (r == r_own) ? l : lo;
            hi = (r == r_own) ? g : hi;
        }
        const int col4 = n0 + t * 16 + (mr & ~3);
        if (col4 < Ncols) {
            const int row = m0 + wv * 16 + q * 4 + r_own;
            unsigned long long pk64 = (unsigned long long)lo | ((unsigned long long)hi << 32);
            *(unsigned long long*)(C + (size_t)row * Ncols + col4) = pk64;
        }
    }
}

// ---------------- ef2a = bf16(lg_ef + repeat(y2n,2)), padded to 64 ----------------
__global__ __launch_bounds__(256) void ef2a_kernel(const float* __restrict__ lg_ef,
                                                   const float* __restrict__ y2n,
                                                   u16* __restrict__ dst) {
    int i = blockIdx.x * 256 + threadIdx.x;
    if (i >= EL * 64) return;
    int e = i >> 6, c = i & 63;
    dst[i] = (c < 40) ? f2bf(lg_ef[(size_t)e * 40 + c] + y2n[(size_t)(e >> 1) * 40 + c]) : (u16)0;
}

// ---------------- edge combine: wave-per-edge, vectorized 16B loads ----------------
// FSMODE: 0 none; 1 fp32 out stride 36 (f<36, e<fsumE); 2 bf16 out stride 64 (e<fsumE).
template <int FSMODE>
__global__ __launch_bounds__(256) void edge_combine_kernel(
    const int* __restrict__ src, const int* __restrict__ dst,
    const u16* __restrict__ Pn, const u16* __restrict__ Pe,
    const float* __restrict__ attn,   // [320]
    float* __restrict__ esc,          // [E][8]
    void* __restrict__ fsum,
    int e0, int CH, int fsumE) {
    const int wid = threadIdx.x >> 6;
    const int lane = threadIdx.x & 63;
    const int idx = blockIdx.x * 4 + wid;
    if (idx >= CH) return;
    const int e = e0 + idx;
    const int lc = (lane < 40) ? lane : 39;
    const int h = lc / 5, o = lc - h * 5;
    const int c = h * 40 + o * 8;
    const bool act = (lane < 40);

    float attn_r[8];
#pragma unroll
    for (int j = 0; j < 8; ++j) attn_r[j] = attn[c + j];

    const int s = src[e], d = dst[e];
    bf16x8 api = *(const bf16x8*)(Pn + (size_t)s * 640 + c);
    bf16x8 apj = *(const bf16x8*)(Pn + (size_t)d * 640 + 320 + c);
    bf16x8 ape = *(const bf16x8*)(Pe + (size_t)idx * 320 + c);

    float v[8];
    float ehp = 0.f;
#pragma unroll
    for (int j = 0; j < 8; ++j) {
        float x = bf2f((u16)api[j]) + bf2f((u16)apj[j]) + bf2f((u16)ape[j]);
        x = x > 0.f ? x : 0.01f * x;   // leaky_relu(0.01)
        v[j] = x;
        ehp += x * attn_r[j];
    }
    float eh = 0.f;
#pragma unroll
    for (int k = 0; k < 5; ++k) eh += __shfl(ehp, h * 5 + k, 64);
    if (act && o == 0) esc[(size_t)e * 8 + h] = eh;

    if (FSMODE != 0 && e < fsumE) {
#pragma unroll
        for (int m = 4; m >= 1; m >>= 1) {
            const int p = (h ^ m) * 5 + o;
#pragma unroll
            for (int j = 0; j < 8; ++j) v[j] += __shfl(v[j], p, 64);
        }
        if (act && h == 0) {
#pragma unroll
            for (int j = 0; j < 8; ++j) {
                const int f = o * 8 + j;
                if (FSMODE == 1) {
                    if (f < 36) ((float*)fsum)[(size_t)e * 36 + f] = v[j];
                } else {
                    ((u16*)fsum)[(size_t)e * 64 + f] = f2bf(v[j]);
                }
            }
        }
    }
}

// ---------------- CSR build ----------------
__global__ __launch_bounds__(256) void hist_kernel(const int* __restrict__ dst,
                                                   int* __restrict__ cnt, int E) {
    int i = blockIdx.x * 256 + threadIdx.x;
    if (i < E) atomicAdd(&cnt[dst[i]], 1);
}

__global__ __launch_bounds__(1024) void scan_block_kernel(const int* __restrict__ cnt,
                                                          int* __restrict__ excl,
                                                          int* __restrict__ bsum, int N) {
    __shared__ int sd[1024];
    const int tid = threadIdx.x;
    const int i = blockIdx.x * 1024 + tid;
    int v = (i < N) ? cnt[i] : 0;
    sd[tid] = v;
    __syncthreads();
    for (int off = 1; off < 1024; off <<= 1) {
        int t = (tid >= off) ? sd[tid - off] : 0;
        __syncthreads();
        sd[tid] += t;
        __syncthreads();
    }
    if (i < N) excl[i] = sd[tid] - v;
    if (tid == 1023) bsum[blockIdx.x] = sd[1023];
}

__global__ void scan_top_kernel(int* __restrict__ bsum, int nblk) {
    if (threadIdx.x == 0 && blockIdx.x == 0) {
        int run = 0;
        for (int b = 0; b < nblk; ++b) {
            int t = bsum[b];
            bsum[b] = run;
            run += t;
        }
    }
}

__global__ __launch_bounds__(256) void scan_add_kernel(int* __restrict__ row_ptr,
                                                       const int* __restrict__ bsum,
                                                       int N, int E) {
    int i = blockIdx.x * 256 + threadIdx.x;
    if (i < N) row_ptr[i] += bsum[i >> 10];
    if (i == 0) row_ptr[N] = E;
}

// scatter: eidx (edge id) + srcs_csr (source node ids, CSR order)
__global__ __launch_bounds__(256) void scatter_kernel(const int* __restrict__ dst,
                                                      const int* __restrict__ src,
                                                      const int* __restrict__ row_ptr,
                                                      int* __restrict__ cur,
                                                      int* __restrict__ eidx,
                                                      int* __restrict__ srcs, int E) {
    int i = blockIdx.x * 256 + threadIdx.x;
    if (i < E) {
        int d = dst[i];
        int pos = row_ptr[d] + atomicAdd(&cur[d], 1);
        eidx[pos] = i;
        srcs[pos] = src[i];
    }
}

// ---------------- CSR softmax: scores (edge order) -> weights in CSR order ----------------
template <int GH>
__global__ __launch_bounds__(256) void csr_softmax_kernel(
    const int* __restrict__ row_ptr, const int* __restrict__ eidx,
    const float* __restrict__ esc, float* __restrict__ wcsr, int N) {
    constexpr int NS = 64 / GH;
    const int wid = threadIdx.x >> 6;
    const int lane = threadIdx.x & 63;
    const int nid = blockIdx.x * 4 + wid;
    if (nid >= N) return;
    const int r0 = row_ptr[nid], r1 = row_ptr[nid + 1];
    const int h = lane & (GH - 1);
    const int slot = lane / GH;

    float mx = -1e30f;
    for (int i = r0 + slot; i < r1; i += NS)
        mx = fmaxf(mx, esc[(size_t)eidx[i] * GH + h]);
#pragma unroll
    for (int m = GH; m < 64; m <<= 1) mx = fmaxf(mx, __shfl_xor(mx, m, 64));

    float den = 0.f;
    for (int i = r0 + slot; i < r1; i += NS)
        den += expf(esc[(size_t)eidx[i] * GH + h] - mx);
#pragma unroll
    for (int m = GH; m < 64; m <<= 1) den += __shfl_xor(den, m, 64);
    const float rden = 1.f / den;

    for (int i = r0 + slot; i < r1; i += NS)
        wcsr[(size_t)i * GH + h] = expf(esc[(size_t)eidx[i] * GH + h] - mx) * rden;
}

// ---------------- node aggregation: 4-edge batched gathers for MLP ----------------
// OM 0: fp32 out stride Fn. OM 1: bf16 out stride 96 zero-padded 92..95.
// Per batch: resolve 4 src rows + 32 weights first, then issue ALL 32 gathered
// uint loads into registers, then FMA. Tail edges padded to last valid (w=0);
// deg >= 1 always (dst contains arange prefix), so r1-1 is valid.
template <int Fn, int GH, int OM>
__global__ __launch_bounds__(256) void node_agg_kernel(
    const int* __restrict__ row_ptr,
    const int* __restrict__ srcs,     // [E] CSR-ordered source node ids
    const float* __restrict__ wcsr,   // [E, GH] CSR-ordered softmax weights
    const u16* __restrict__ Pnode,    // [N, GH*Fn] bf16
    void* __restrict__ outp, int N) {
    constexpr int PAIRS = Fn / 2;     // Fn even: 20 / 46
    constexpr int STR = GH * Fn;
    const int wid = threadIdx.x >> 6;
    const int lane = threadIdx.x & 63;
    const int nid = blockIdx.x * 4 + wid;
    if (nid >= N) return;
    const int r0 = row_ptr[nid], r1 = row_ptr[nid + 1];
    const int col = 2 * lane;
    const bool act = (lane < PAIRS);

    float a0 = 0.f, a1 = 0.f;
    for (int i = r0; i < r1; i += 4) {
        const u16* prs[4];
        float wv[4][GH];
#pragma unroll
        for (int b = 0; b < 4; ++b) {
            const int ii = (i + b < r1) ? (i + b) : (r1 - 1);
            prs[b] = Pnode + (size_t)srcs[ii] * STR;
            const float live = (i + b < r1) ? 1.f : 0.f;
            const float* wp = wcsr + (size_t)ii * GH;
#pragma unroll
            for (int hh = 0; hh < GH; ++hh) wv[b][hh] = wp[hh] * live;
        }
        if (act) {
            unsigned pv[4][GH];
#pragma unroll
            for (int b = 0; b < 4; ++b)
#pragma unroll
                for (int hh = 0; hh < GH; ++hh)
                    pv[b][hh] = *(const unsigned*)(prs[b] + hh * Fn + col);
#pragma unroll
            for (int b = 0; b < 4; ++b)
#pragma unroll
                for (int hh = 0; hh < GH; ++hh) {
                    a0 += wv[b][hh] * bf2f((u16)(pv[b][hh] & 0xFFFFu));
                    a1 += wv[b][hh] * bf2f((u16)(pv[b][hh] >> 16));
                }
        }
    }
    if (OM == 0) {
        if (act) {
            float* op = (float*)outp + (size_t)nid * Fn + col;
            op[0] = a0;
            op[1] = a1;
        }
    } else {
        unsigned* ob = (unsigned*)((u16*)outp + (size_t)nid * 96);
        if (act) {
            unsigned pk = (unsigned)f2bf(a0) | ((unsigned)f2bf(a1) << 16);
            ob[lane] = pk;
        } else if (lane < 48) {
            ob[lane] = 0u;
        }
    }
}

// ---------------- readout ----------------
__global__ __launch_bounds__(256) void readout_kernel(const u16* __restrict__ nfb,
                                                      const float* __restrict__ y22p,
                                                      const float* __restrict__ Wr1,
                                                      const float* __restrict__ br1,
                                                      const float* __restrict__ Wr2,
                                                      const float* __restrict__ br2,
                                                      float* __restrict__ out) {
    const int b = blockIdx.x;
    const int t = threadIdx.x;
    __shared__ float y[128];
    __shared__ float hh[128];
    __shared__ float red[128];
    if (t < 92) {
        float s = 0.f;
        const u16* base = nfb + (size_t)b * 600 * 96 + t;
        for (int i = 0; i < 600; ++i) s += bf2f(base[(size_t)i * 96]);
        y[t] = s * (1.f / 600.f);
    } else if (t >= 128 && t < 164) {
        int f = t - 128;
        float s = 0.f;
        const float* base = y22p + (size_t)b * 1200 * 36 + f;
        for (int i = 0; i < 1200; ++i) s += base[(size_t)i * 36];
        y[92 + f] = s * (1.f / 1200.f);
    }
    __syncthreads();
    if (t < 128) {
        float s = br1[t];
        for (int c = 0; c < 128; ++c) s += y[c] * Wr1[(size_t)c * 128 + t];
        hh[t] = sigmoidf(s);
    }
    __syncthreads();
    if (t < 128) red[t] = hh[t] * Wr2[t];
    __syncthreads();
    for (int k = 64; k > 0; k >>= 1) {
        if (t < k) red[t] += red[t + k];
        __syncthreads();
    }
    if (t == 0) out[b] = sigmoidf(red[0] + br2[0]);
}

// ---------------- host side ----------------
static inline int cdiv(int a, int b) { return (a + b - 1) / b; }

extern "C" void kernel_launch(void* const* d_in, const int* in_sizes, int n_in,
                              void* d_out, int out_size, void* d_ws, size_t ws_size,
                              hipStream_t stream) {
    const int* gg_src = (const int*)d_in[0];
    const int* gg_dst = (const int*)d_in[1];
    const float* gg_nf = (const float*)d_in[2];
    const float* gg_ef = (const float*)d_in[3];
    const int* lg_src = (const int*)d_in[4];
    const int* lg_dst = (const int*)d_in[5];
    const float* lg_nf = (const float*)d_in[6];
    const float* lg_ef = (const float*)d_in[7];
    const float* W_node1 = (const float*)d_in[8];
    const float* b_node1 = (const float*)d_in[9];
    const float* W_ni1 = (const float*)d_in[10];
    const float* W_nj1 = (const float*)d_in[11];
    const float* W_fij1 = (const float*)d_in[12];
    const float* attn1 = (const float*)d_in[13];
    const float* bias1 = (const float*)d_in[14];
    const float* W_node2a = (const float*)d_in[15];
    const float* b_node2a = (const float*)d_in[16];
    const float* W_ni2a = (const float*)d_in[17];
    const float* W_nj2a = (const float*)d_in[18];
    const float* W_fij2a = (const float*)d_in[19];
    const float* attn2a = (const float*)d_in[20];
    const float* bias2a = (const float*)d_in[21];
    const float* W_node2b = (const float*)d_in[22];
    const float* b_node2b = (const float*)d_in[23];
    const float* W_ni2b = (const float*)d_in[24];
    const float* W_nj2b = (const float*)d_in[25];
    const float* W_fij2b = (const float*)d_in[26];
    const float* attn2b = (const float*)d_in[27];
    const float* bias2b = (const float*)d_in[28];
    const float* Wr1 = (const float*)d_in[29];
    const float* br1 = (const float*)d_in[30];
    const float* Wr2 = (const float*)d_in[31];
    const float* br2 = (const float*)d_in[32];
    float* out = (float*)d_out;

    char* ws = (char*)d_ws;
    size_t off = 0;
    auto take = [&](size_t bytes) {
        size_t o = off;
        off += (bytes + 255) & ~(size_t)255;
        return (void*)(ws + o);
    };
    float* y2n = (float*)take((size_t)NG * 40 * 4);
    float* y22p = (float*)take((size_t)NG * 36 * 4);
    float* esc = (float*)take((size_t)EG * 8 * 4);
    float* wcsr = (float*)take((size_t)EG * 8 * 4);
    int* gg_row = (int*)take((size_t)(NG + 1) * 4);
    int* gg_eidx = (int*)take((size_t)EG * 4);
    int* gg_srcs = (int*)take((size_t)EG * 4);
    int* gg_cnt = (int*)take((size_t)NG * 4);
    int* lg_row = (int*)take((size_t)(NL + 1) * 4);
    int* lg_eidx = (int*)take((size_t)EL * 4);
    int* lg_srcs = (int*)take((size_t)EL * 4);
    int* lg_cnt = (int*)take((size_t)NL * 4);
    int* bsum = (int*)take((size_t)128 * 4);
    u16* gg_nf_bf = (u16*)take((size_t)NG * 64 * 2);
    u16* gg_ef_bf = (u16*)take((size_t)EG * 32 * 2);
    u16* lg_nf_bf = (u16*)take((size_t)NL * 96 * 2);
    u16* nfa_bf = (u16*)take((size_t)NL * 96 * 2);
    u16* nfb_bf = (u16*)take((size_t)NL * 96 * 2);
    u16* ef_shared = (u16*)take((size_t)EL * 64 * 2);   // ef2a input, then efa fsum
    u16* wt_ninj1 = (u16*)take((size_t)640 * 64 * 2);
    u16* wt_node1 = (u16*)take((size_t)320 * 64 * 2);
    u16* wt_fij1 = (u16*)take((size_t)320 * 32 * 2);
    u16* wt_ninj2a = (u16*)take((size_t)640 * 96 * 2);
    u16* wt_ninj2b = (u16*)take((size_t)640 * 96 * 2);
    u16* wt_fij2a = (u16*)take((size_t)320 * 64 * 2);
    u16* wt_fij2b = (u16*)take((size_t)320 * 64 * 2);
    u16* wt_node2a = (u16*)take((size_t)768 * 96 * 2);
    u16* wt_node2b = (u16*)take((size_t)768 * 96 * 2);
    float* attn_p1 = (float*)take((size_t)320 * 4);
    float* bias_cat1 = (float*)take((size_t)640 * 4);
    float* bias_cat2a = (float*)take((size_t)640 * 4);
    float* bias_cat2b = (float*)take((size_t)640 * 4);
    u16* slab = (u16*)take(((size_t)NG * 640 + (size_t)(EG / 4) * 320) * 2);  // 147.5 MB

    auto cvt = [&](const float* s, u16* d, int M, int K, int Kpad) {
        convert_pad_kernel<<<cdiv(M * Kpad, 256), 256, 0, stream>>>(s, d, M, K, Kpad);
    };
    auto wtr = [&](const float* W, int ldw, u16* d, int K, int N, int Nalloc, int Kpad) {
        wtrans_kernel<<<cdiv(Nalloc * Kpad, 256), 256, 0, stream>>>(W, ldw, d, K, N, Nalloc, Kpad);
    };
    auto build_csr = [&](const int* dst, const int* src, int* row_ptr, int* eidx, int* srcs,
                         int* cnt, int N, int E) {
        hipMemsetAsync(cnt, 0, (size_t)N * 4, stream);
        hist_kernel<<<cdiv(E, 256), 256, 0, stream>>>(dst, cnt, E);
        int nblk = cdiv(N, 1024);
        scan_block_kernel<<<nblk, 1024, 0, stream>>>(cnt, row_ptr, bsum, N);
        scan_top_kernel<<<1, 64, 0, stream>>>(bsum, nblk);
        scan_add_kernel<<<cdiv(N, 256), 256, 0, stream>>>(row_ptr, bsum, N, E);
        hipMemsetAsync(cnt, 0, (size_t)N * 4, stream);
        scatter_kernel<<<cdiv(E, 256), 256, 0, stream>>>(dst, src, row_ptr, cnt, eidx, srcs, E);
    };

    build_csr(gg_dst, gg_src, gg_row, gg_eidx, gg_srcs, gg_cnt, NG, EG);
    build_csr(lg_dst, lg_src, lg_row, lg_eidx, lg_srcs, lg_cnt, NL, EL);

    // prep: conversions + weight transforms + meta
    cvt(gg_nf, gg_nf_bf, NG, 40, 64);
    cvt(gg_ef, gg_ef_bf, EG, 10, 32);
    cvt(lg_nf, lg_nf_bf, NL, 92, 96);
    wtrans_hp_kernel<<<cdiv(320 * 64, 256), 256, 0, stream>>>(W_ni1, 288, wt_ninj1, 40, 64);
    wtrans_hp_kernel<<<cdiv(320 * 64, 256), 256, 0, stream>>>(W_nj1, 288, wt_ninj1 + 320 * 64, 40, 64);
    wtrans_hp_kernel<<<cdiv(320 * 32, 256), 256, 0, stream>>>(W_fij1, 288, wt_fij1, 10, 32);
    wtr(W_node1, 320, wt_node1, 40, 320, 320, 64);
    wtr(W_ni2a, 320, wt_ninj2a, 92, 320, 320, 96);
    wtr(W_nj2a, 320, wt_ninj2a + 320 * 96, 92, 320, 320, 96);
    wtr(W_ni2b, 320, wt_ninj2b, 92, 320, 320, 96);
    wtr(W_nj2b, 320, wt_ninj2b + 320 * 96, 92, 320, 320, 96);
    wtr(W_fij2a, 320, wt_fij2a, 40, 320, 320, 64);
    wtr(W_fij2b, 320, wt_fij2b, 40, 320, 320, 64);
    wtr(W_node2a, 736, wt_node2a, 92, 736, 768, 96);
    wtr(W_node2b, 736, wt_node2b, 92, 736, 768, 96);
    meta_kernel<<<cdiv(2240, 256), 256, 0, stream>>>(attn1, bias1, bias2a, bias2b,
                                                     attn_p1, bias_cat1, bias_cat2a, bias_cat2b);

    // ---------------- stage 1 (gg): single pass, 8 heads (FE padded 36->40) ----------------
    {
        u16* Pn1 = slab;                                  // [NG][640]
        u16* Pe1 = slab + (size_t)NG * 640;               // [EG/4][320] chunk
        gemm_bf_kernel<64><<<dim3(NG / 64, 10), 256, 0, stream>>>(
            gg_nf_bf, wt_ninj1, bias_cat1, Pn1, 640);
        for (int ch = 0; ch < 4; ++ch) {
            const int e0 = ch * (EG / 4);
            gemm_bf_kernel<32><<<dim3((EG / 4) / 64, 5), 256, 0, stream>>>(
                gg_ef_bf + (size_t)e0 * 32, wt_fij1, nullptr, Pe1, 320);
            edge_combine_kernel<1><<<(EG / 4) / 4, 256, 0, stream>>>(
                gg_src, gg_dst, Pn1, Pe1, attn_p1, esc, y22p, e0, EG / 4, NG);
        }
        csr_softmax_kernel<8><<<NG / 4, 256, 0, stream>>>(gg_row, gg_eidx, esc, wcsr, NG);
        u16* Pnode1 = slab;   // alias: Pn1/Pe1 dead
        gemm_bf_kernel<64><<<dim3(NG / 64, 5), 256, 0, stream>>>(
            gg_nf_bf, wt_node1, b_node1, Pnode1, 320);
        node_agg_kernel<40, 8, 0><<<NG / 4, 256, 0, stream>>>(gg_row, gg_srcs, wcsr,
                                                              Pnode1, y2n, NG);
    }

    // ef for lg layer 2a
    ef2a_kernel<<<cdiv(EL * 64, 256), 256, 0, stream>>>(lg_ef, y2n, ef_shared);

    // ---------------- stage 2 (lg), two layers ----------------
    for (int layer = 0; layer < 2; ++layer) {
        const bool a = (layer == 0);
        const u16* nf_in = a ? lg_nf_bf : nfa_bf;
        const u16* Wninj = a ? wt_ninj2a : wt_ninj2b;
        const u16* Wfij = a ? wt_fij2a : wt_fij2b;
        const u16* Wnode = a ? wt_node2a : wt_node2b;
        const float* bn = a ? b_node2a : b_node2b;
        const float* bcat = a ? bias_cat2a : bias_cat2b;
        const float* at = a ? attn2a : attn2b;
        u16* nf_out = a ? nfa_bf : nfb_bf;

        u16* Pn2 = slab;                                  // [NL][640]
        u16* Pe2 = slab + (size_t)NL * 640;               // [EL][320]
        gemm_bf_kernel<96><<<dim3(NL / 64, 10), 256, 0, stream>>>(nf_in, Wninj, bcat, Pn2, 640);
        gemm_bf_kernel<64><<<dim3(EL / 64, 5), 256, 0, stream>>>(ef_shared, Wfij, nullptr, Pe2, 320);
        if (a)
            edge_combine_kernel<2><<<EL / 4, 256, 0, stream>>>(
                lg_src, lg_dst, Pn2, Pe2, at, esc, ef_shared, 0, EL, EL);
        else
            edge_combine_kernel<0><<<EL / 4, 256, 0, stream>>>(
                lg_src, lg_dst, Pn2, Pe2, at, esc, nullptr, 0, EL, 0);
        csr_softmax_kernel<8><<<NL / 4, 256, 0, stream>>>(lg_row, lg_eidx, esc, wcsr, NL);
        u16* Pnode2 = slab;   // alias: Pn2/Pe2 dead
        gemm_bf_kernel<96><<<dim3(NL / 64, 12), 256, 0, stream>>>(nf_in, Wnode, bn, Pnode2, 736);
        node_agg_kernel<92, 8, 1><<<NL / 4, 256, 0, stream>>>(lg_row, lg_srcs, wcsr,
                                                              Pnode2, nf_out, NL);
    }

    // ---------------- readout ----------------
    readout_kernel<<<NB, 256, 0, stream>>>(nfb_bf, y22p, Wr1, br1, Wr2, br2, out);
}

// Round 3
// 1102.142 us; speedup vs baseline: 1.0777x; 1.0777x over previous
//
#include <hip/hip_runtime.h>
#include <math.h>

#define NG 76800
#define EG 307200
#define NL 38400
#define EL 153600
#define NB 64
#define NH 8

typedef __attribute__((ext_vector_type(8))) short bf16x8;
typedef __attribute__((ext_vector_type(4))) float f32x4;
typedef unsigned short u16;

__device__ __forceinline__ float sigmoidf(float x) { return 1.f / (1.f + expf(-x)); }
__device__ __forceinline__ u16 f2bf(float x) {
    unsigned u = __float_as_uint(x);
    return (u16)((u + 0x7FFFu + ((u >> 16) & 1u)) >> 16);
}
__device__ __forceinline__ float bf2f(u16 v) { return __uint_as_float(((unsigned)v) << 16); }

// ---------------- fp32 -> padded bf16 [M x Kpad] ----------------
__global__ __launch_bounds__(256) void convert_pad_kernel(const float* __restrict__ src,
                                                          u16* __restrict__ dst,
                                                          int M, int K, int Kpad) {
    int i = blockIdx.x * 256 + threadIdx.x;
    if (i >= M * Kpad) return;
    int m = i / Kpad, k = i - m * Kpad;
    dst[i] = (k < K) ? f2bf(src[(size_t)m * K + k]) : (u16)0;
}

// ---------------- W[K x Nfull] -> bf16 Wt[Nalloc x Kpad] (zero padded) ----------------
__global__ __launch_bounds__(256) void wtrans_kernel(const float* __restrict__ W, int ldw,
                                                     u16* __restrict__ dst,
                                                     int K, int N, int Nalloc, int Kpad) {
    int i = blockIdx.x * 256 + threadIdx.x;
    if (i >= Nalloc * Kpad) return;
    int n = i / Kpad, k = i - n * Kpad;
    dst[i] = (n < N && k < K) ? f2bf(W[(size_t)k * ldw + n]) : (u16)0;
}

// ---------------- head-padded transform: FE 36->40, 8 heads, R=320 rows ----------------
__global__ __launch_bounds__(256) void wtrans_hp_kernel(const float* __restrict__ W, int ldw,
                                                        u16* __restrict__ dst,
                                                        int K, int Kpad) {
    int i = blockIdx.x * 256 + threadIdx.x;
    if (i >= 320 * Kpad) return;
    int n = i / Kpad, k = i - n * Kpad;
    int hh = n / 40, f = n - hh * 40;
    float v = (k < K && f < 36) ? W[(size_t)k * ldw + hh * 36 + f] : 0.f;
    dst[i] = f2bf(v);
}

// ---------------- meta: padded attn1 + concat biases ----------------
__global__ __launch_bounds__(256) void meta_kernel(const float* __restrict__ attn1,
                                                   const float* __restrict__ bias1,
                                                   const float* __restrict__ b2a,
                                                   const float* __restrict__ b2b,
                                                   float* __restrict__ attn_p1,
                                                   float* __restrict__ bias_cat1,
                                                   float* __restrict__ bias_cat2a,
                                                   float* __restrict__ bias_cat2b) {
    int i = blockIdx.x * 256 + threadIdx.x;
    if (i < 320) {
        int hh = i / 40, f = i - hh * 40;
        attn_p1[i] = (f < 36) ? attn1[hh * 36 + f] : 0.f;
    } else if (i < 960) {
        int j = i - 320;
        float v = 0.f;
        if (j < 320) {
            int hh = j / 40, f = j - hh * 40;
            v = (f < 36) ? bias1[hh * 36 + f] : 0.f;
        }
        bias_cat1[j] = v;
    } else if (i < 1600) {
        int j = i - 960;
        bias_cat2a[j] = (j < 320) ? b2a[j] : 0.f;
    } else if (i < 2240) {
        int j = i - 1600;
        bias_cat2b[j] = (j < 320) ? b2b[j] : 0.f;
    }
}

// ---------------- LDS-free bf16 MFMA GEMM, LDS-staged full-line epilogue ----------------
// Each wave stages its 16x64 bf16 output tile in LDS (2KB), then reads back
// row-major (ds_read_b128) and stores full 128B lines (8 lanes x 16B per row).
// Nstride: row stride of C in elements (>= Ncols, *2 must be mult of 128B for
// line alignment: 320->640B, 640->1280B, 768->1536B).
template <int KPAD>
__global__ __launch_bounds__(256) void gemm_bf_kernel(const u16* __restrict__ A,
                                                      const u16* __restrict__ Wt,
                                                      const float* __restrict__ bias,
                                                      u16* __restrict__ C, int Ncols,
                                                      int Nstride) {
    __shared__ u16 st[4][16 * 64];
    const int m0 = blockIdx.x * 64;
    const int n0 = blockIdx.y * 64;
    const int wv = threadIdx.x >> 6;
    const int lane = threadIdx.x & 63;
    const int q = lane >> 4;
    const int mr = lane & 15;

    const u16* Arow = A + (size_t)(m0 + wv * 16 + mr) * KPAD;
    f32x4 acc[4];
#pragma unroll
    for (int t = 0; t < 4; ++t) acc[t] = (f32x4){0.f, 0.f, 0.f, 0.f};

#pragma unroll
    for (int k0 = 0; k0 < KPAD; k0 += 32) {
        bf16x8 af = *(const bf16x8*)(Arow + k0 + q * 8);
#pragma unroll
        for (int t = 0; t < 4; ++t) {
            bf16x8 bv = *(const bf16x8*)(Wt + (size_t)(n0 + t * 16 + mr) * KPAD + k0 + q * 8);
            acc[t] = __builtin_amdgcn_mfma_f32_16x16x32_bf16(af, bv, acc[t], 0, 0, 0);
        }
    }

    u16* myst = st[wv];
#pragma unroll
    for (int t = 0; t < 4; ++t) {
        const int colme = n0 + t * 16 + mr;
        const float bb = (bias && colme < Ncols) ? bias[colme] : 0.f;
#pragma unroll
        for (int r = 0; r < 4; ++r)
            myst[(q * 4 + r) * 64 + t * 16 + mr] = f2bf(acc[t][r] + bb);
    }
    // wave-private region: same-wave LDS ordering via lgkmcnt, no barrier needed
    const int rrow = lane >> 3;        // 0..7
    const int rcol = (lane & 7) * 8;   // 0,8,..,56
    bf16x8 v0 = *(const bf16x8*)(myst + rrow * 64 + rcol);
    bf16x8 v1 = *(const bf16x8*)(myst + (rrow + 8) * 64 + rcol);
    const int gcol = n0 + rcol;
    if (gcol < Ncols) {
        const int grow = m0 + wv * 16 + rrow;
        *(bf16x8*)(C + (size_t)grow * Nstride + gcol) = v0;
        *(bf16x8*)(C + (size_t)(grow + 8) * Nstride + gcol) = v1;
    }
}

// ---------------- ef2a = bf16(lg_ef + repeat(y2n,2)), padded to 64 ----------------
__global__ __launch_bounds__(256) void ef2a_kernel(const float* __restrict__ lg_ef,
                                                   const float* __restrict__ y2n,
                                                   u16* __restrict__ dst) {
    int i = blockIdx.x * 256 + threadIdx.x;
    if (i >= EL * 64) return;
    int e = i >> 6, c = i & 63;
    dst[i] = (c < 40) ? f2bf(lg_ef[(size_t)e * 40 + c] + y2n[(size_t)(e >> 1) * 40 + c]) : (u16)0;
}

// ---------------- edge combine: wave-per-edge, vectorized 16B loads ----------------
// FSMODE: 0 none; 1 fp32 out stride 36 (f<36, e<fsumE); 2 bf16 out stride 64 (e<fsumE).
template <int FSMODE>
__global__ __launch_bounds__(256) void edge_combine_kernel(
    const int* __restrict__ src, const int* __restrict__ dst,
    const u16* __restrict__ Pn, const u16* __restrict__ Pe,
    const float* __restrict__ attn,   // [320]
    float* __restrict__ esc,          // [E][8]
    void* __restrict__ fsum,
    int e0, int CH, int fsumE) {
    const int wid = threadIdx.x >> 6;
    const int lane = threadIdx.x & 63;
    const int idx = blockIdx.x * 4 + wid;
    if (idx >= CH) return;
    const int e = e0 + idx;
    const int lc = (lane < 40) ? lane : 39;
    const int h = lc / 5, o = lc - h * 5;
    const int c = h * 40 + o * 8;
    const bool act = (lane < 40);

    float attn_r[8];
#pragma unroll
    for (int j = 0; j < 8; ++j) attn_r[j] = attn[c + j];

    const int s = src[e], d = dst[e];
    bf16x8 api = *(const bf16x8*)(Pn + (size_t)s * 640 + c);
    bf16x8 apj = *(const bf16x8*)(Pn + (size_t)d * 640 + 320 + c);
    bf16x8 ape = *(const bf16x8*)(Pe + (size_t)idx * 320 + c);

    float v[8];
    float ehp = 0.f;
#pragma unroll
    for (int j = 0; j < 8; ++j) {
        float x = bf2f((u16)api[j]) + bf2f((u16)apj[j]) + bf2f((u16)ape[j]);
        x = x > 0.f ? x : 0.01f * x;   // leaky_relu(0.01)
        v[j] = x;
        ehp += x * attn_r[j];
    }
    float eh = 0.f;
#pragma unroll
    for (int k = 0; k < 5; ++k) eh += __shfl(ehp, h * 5 + k, 64);
    if (act && o == 0) esc[(size_t)e * 8 + h] = eh;

    if (FSMODE != 0 && e < fsumE) {
#pragma unroll
        for (int m = 4; m >= 1; m >>= 1) {
            const int p = (h ^ m) * 5 + o;
#pragma unroll
            for (int j = 0; j < 8; ++j) v[j] += __shfl(v[j], p, 64);
        }
        if (act && h == 0) {
#pragma unroll
            for (int j = 0; j < 8; ++j) {
                const int f = o * 8 + j;
                if (FSMODE == 1) {
                    if (f < 36) ((float*)fsum)[(size_t)e * 36 + f] = v[j];
                } else {
                    ((u16*)fsum)[(size_t)e * 64 + f] = f2bf(v[j]);
                }
            }
        }
    }
}

// ---------------- CSR build ----------------
__global__ __launch_bounds__(256) void hist_kernel(const int* __restrict__ dst,
                                                   int* __restrict__ cnt, int E) {
    int i = blockIdx.x * 256 + threadIdx.x;
    if (i < E) atomicAdd(&cnt[dst[i]], 1);
}

__global__ __launch_bounds__(1024) void scan_block_kernel(const int* __restrict__ cnt,
                                                          int* __restrict__ excl,
                                                          int* __restrict__ bsum, int N) {
    __shared__ int sd[1024];
    const int tid = threadIdx.x;
    const int i = blockIdx.x * 1024 + tid;
    int v = (i < N) ? cnt[i] : 0;
    sd[tid] = v;
    __syncthreads();
    for (int off = 1; off < 1024; off <<= 1) {
        int t = (tid >= off) ? sd[tid - off] : 0;
        __syncthreads();
        sd[tid] += t;
        __syncthreads();
    }
    if (i < N) excl[i] = sd[tid] - v;
    if (tid == 1023) bsum[blockIdx.x] = sd[1023];
}

__global__ void scan_top_kernel(int* __restrict__ bsum, int nblk) {
    if (threadIdx.x == 0 && blockIdx.x == 0) {
        int run = 0;
        for (int b = 0; b < nblk; ++b) {
            int t = bsum[b];
            bsum[b] = run;
            run += t;
        }
    }
}

__global__ __launch_bounds__(256) void scan_add_kernel(int* __restrict__ row_ptr,
                                                       const int* __restrict__ bsum,
                                                       int N, int E) {
    int i = blockIdx.x * 256 + threadIdx.x;
    if (i < N) row_ptr[i] += bsum[i >> 10];
    if (i == 0) row_ptr[N] = E;
}

// scatter: eidx (edge id) + srcs_csr (source node ids, CSR order)
__global__ __launch_bounds__(256) void scatter_kernel(const int* __restrict__ dst,
                                                      const int* __restrict__ src,
                                                      const int* __restrict__ row_ptr,
                                                      int* __restrict__ cur,
                                                      int* __restrict__ eidx,
                                                      int* __restrict__ srcs, int E) {
    int i = blockIdx.x * 256 + threadIdx.x;
    if (i < E) {
        int d = dst[i];
        int pos = row_ptr[d] + atomicAdd(&cur[d], 1);
        eidx[pos] = i;
        srcs[pos] = src[i];
    }
}

// ---------------- CSR softmax: scores (edge order) -> weights in CSR order ----------------
template <int GH>
__global__ __launch_bounds__(256) void csr_softmax_kernel(
    const int* __restrict__ row_ptr, const int* __restrict__ eidx,
    const float* __restrict__ esc, float* __restrict__ wcsr, int N) {
    constexpr int NS = 64 / GH;
    const int wid = threadIdx.x >> 6;
    const int lane = threadIdx.x & 63;
    const int nid = blockIdx.x * 4 + wid;
    if (nid >= N) return;
    const int r0 = row_ptr[nid], r1 = row_ptr[nid + 1];
    const int h = lane & (GH - 1);
    const int slot = lane / GH;

    float mx = -1e30f;
    for (int i = r0 + slot; i < r1; i += NS)
        mx = fmaxf(mx, esc[(size_t)eidx[i] * GH + h]);
#pragma unroll
    for (int m = GH; m < 64; m <<= 1) mx = fmaxf(mx, __shfl_xor(mx, m, 64));

    float den = 0.f;
    for (int i = r0 + slot; i < r1; i += NS)
        den += expf(esc[(size_t)eidx[i] * GH + h] - mx);
#pragma unroll
    for (int m = GH; m < 64; m <<= 1) den += __shfl_xor(den, m, 64);
    const float rden = 1.f / den;

    for (int i = r0 + slot; i < r1; i += NS)
        wcsr[(size_t)i * GH + h] = expf(esc[(size_t)eidx[i] * GH + h] - mx) * rden;
}

// ---------------- node aggregation: 4-edge batched gathers for MLP ----------------
// OM 0: fp32 out stride Fn. OM 1: bf16 out stride 96 zero-padded 92..95.
// STR: row stride (elements) of Pnode (>= GH*Fn; 768 for lg to keep GEMM
// output rows 128B-aligned).
template <int Fn, int GH, int OM, int STR>
__global__ __launch_bounds__(256) void node_agg_kernel(
    const int* __restrict__ row_ptr,
    const int* __restrict__ srcs,     // [E] CSR-ordered source node ids
    const float* __restrict__ wcsr,   // [E, GH] CSR-ordered softmax weights
    const u16* __restrict__ Pnode,    // [N, STR] bf16
    void* __restrict__ outp, int N) {
    constexpr int PAIRS = Fn / 2;     // Fn even: 20 / 46
    const int wid = threadIdx.x >> 6;
    const int lane = threadIdx.x & 63;
    const int nid = blockIdx.x * 4 + wid;
    if (nid >= N) return;
    const int r0 = row_ptr[nid], r1 = row_ptr[nid + 1];
    const int col = 2 * lane;
    const bool act = (lane < PAIRS);

    float a0 = 0.f, a1 = 0.f;
    for (int i = r0; i < r1; i += 4) {
        const u16* prs[4];
        float wv[4][GH];
#pragma unroll
        for (int b = 0; b < 4; ++b) {
            const int ii = (i + b < r1) ? (i + b) : (r1 - 1);
            prs[b] = Pnode + (size_t)srcs[ii] * STR;
            const float live = (i + b < r1) ? 1.f : 0.f;
            const float* wp = wcsr + (size_t)ii * GH;
#pragma unroll
            for (int hh = 0; hh < GH; ++hh) wv[b][hh] = wp[hh] * live;
        }
        if (act) {
            unsigned pv[4][GH];
#pragma unroll
            for (int b = 0; b < 4; ++b)
#pragma unroll
                for (int hh = 0; hh < GH; ++hh)
                    pv[b][hh] = *(const unsigned*)(prs[b] + hh * Fn + col);
#pragma unroll
            for (int b = 0; b < 4; ++b)
#pragma unroll
                for (int hh = 0; hh < GH; ++hh) {
                    a0 += wv[b][hh] * bf2f((u16)(pv[b][hh] & 0xFFFFu));
                    a1 += wv[b][hh] * bf2f((u16)(pv[b][hh] >> 16));
                }
        }
    }
    if (OM == 0) {
        if (act) {
            float* op = (float*)outp + (size_t)nid * Fn + col;
            op[0] = a0;
            op[1] = a1;
        }
    } else {
        unsigned* ob = (unsigned*)((u16*)outp + (size_t)nid * 96);
        if (act) {
            unsigned pk = (unsigned)f2bf(a0) | ((unsigned)f2bf(a1) << 16);
            ob[lane] = pk;
        } else if (lane < 48) {
            ob[lane] = 0u;
        }
    }
}

// ---------------- readout ----------------
__global__ __launch_bounds__(256) void readout_kernel(const u16* __restrict__ nfb,
                                                      const float* __restrict__ y22p,
                                                      const float* __restrict__ Wr1,
                                                      const float* __restrict__ br1,
                                                      const float* __restrict__ Wr2,
                                                      const float* __restrict__ br2,
                                                      float* __restrict__ out) {
    const int b = blockIdx.x;
    const int t = threadIdx.x;
    __shared__ float y[128];
    __shared__ float hh[128];
    __shared__ float red[128];
    if (t < 92) {
        float s = 0.f;
        const u16* base = nfb + (size_t)b * 600 * 96 + t;
        for (int i = 0; i < 600; ++i) s += bf2f(base[(size_t)i * 96]);
        y[t] = s * (1.f / 600.f);
    } else if (t >= 128 && t < 164) {
        int f = t - 128;
        float s = 0.f;
        const float* base = y22p + (size_t)b * 1200 * 36 + f;
        for (int i = 0; i < 1200; ++i) s += base[(size_t)i * 36];
        y[92 + f] = s * (1.f / 1200.f);
    }
    __syncthreads();
    if (t < 128) {
        float s = br1[t];
        for (int c = 0; c < 128; ++c) s += y[c] * Wr1[(size_t)c * 128 + t];
        hh[t] = sigmoidf(s);
    }
    __syncthreads();
    if (t < 128) red[t] = hh[t] * Wr2[t];
    __syncthreads();
    for (int k = 64; k > 0; k >>= 1) {
        if (t < k) red[t] += red[t + k];
        __syncthreads();
    }
    if (t == 0) out[b] = sigmoidf(red[0] + br2[0]);
}

// ---------------- host side ----------------
static inline int cdiv(int a, int b) { return (a + b - 1) / b; }

extern "C" void kernel_launch(void* const* d_in, const int* in_sizes, int n_in,
                              void* d_out, int out_size, void* d_ws, size_t ws_size,
                              hipStream_t stream) {
    const int* gg_src = (const int*)d_in[0];
    const int* gg_dst = (const int*)d_in[1];
    const float* gg_nf = (const float*)d_in[2];
    const float* gg_ef = (const float*)d_in[3];
    const int* lg_src = (const int*)d_in[4];
    const int* lg_dst = (const int*)d_in[5];
    const float* lg_nf = (const float*)d_in[6];
    const float* lg_ef = (const float*)d_in[7];
    const float* W_node1 = (const float*)d_in[8];
    const float* b_node1 = (const float*)d_in[9];
    const float* W_ni1 = (const float*)d_in[10];
    const float* W_nj1 = (const float*)d_in[11];
    const float* W_fij1 = (const float*)d_in[12];
    const float* attn1 = (const float*)d_in[13];
    const float* bias1 = (const float*)d_in[14];
    const float* W_node2a = (const float*)d_in[15];
    const float* b_node2a = (const float*)d_in[16];
    const float* W_ni2a = (const float*)d_in[17];
    const float* W_nj2a = (const float*)d_in[18];
    const float* W_fij2a = (const float*)d_in[19];
    const float* attn2a = (const float*)d_in[20];
    const float* bias2a = (const float*)d_in[21];
    const float* W_node2b = (const float*)d_in[22];
    const float* b_node2b = (const float*)d_in[23];
    const float* W_ni2b = (const float*)d_in[24];
    const float* W_nj2b = (const float*)d_in[25];
    const float* W_fij2b = (const float*)d_in[26];
    const float* attn2b = (const float*)d_in[27];
    const float* bias2b = (const float*)d_in[28];
    const float* Wr1 = (const float*)d_in[29];
    const float* br1 = (const float*)d_in[30];
    const float* Wr2 = (const float*)d_in[31];
    const float* br2 = (const float*)d_in[32];
    float* out = (float*)d_out;

    char* ws = (char*)d_ws;
    size_t off = 0;
    auto take = [&](size_t bytes) {
        size_t o = off;
        off += (bytes + 255) & ~(size_t)255;
        return (void*)(ws + o);
    };
    float* y2n = (float*)take((size_t)NG * 40 * 4);
    float* y22p = (float*)take((size_t)NG * 36 * 4);
    float* esc = (float*)take((size_t)EG * 8 * 4);
    float* wcsr = (float*)take((size_t)EG * 8 * 4);
    int* gg_row = (int*)take((size_t)(NG + 1) * 4);
    int* gg_eidx = (int*)take((size_t)EG * 4);
    int* gg_srcs = (int*)take((size_t)EG * 4);
    int* gg_cnt = (int*)take((size_t)NG * 4);
    int* lg_row = (int*)take((size_t)(NL + 1) * 4);
    int* lg_eidx = (int*)take((size_t)EL * 4);
    int* lg_srcs = (int*)take((size_t)EL * 4);
    int* lg_cnt = (int*)take((size_t)NL * 4);
    int* bsum = (int*)take((size_t)128 * 4);
    u16* gg_nf_bf = (u16*)take((size_t)NG * 64 * 2);
    u16* gg_ef_bf = (u16*)take((size_t)EG * 32 * 2);
    u16* lg_nf_bf = (u16*)take((size_t)NL * 96 * 2);
    u16* nfa_bf = (u16*)take((size_t)NL * 96 * 2);
    u16* nfb_bf = (u16*)take((size_t)NL * 96 * 2);
    u16* ef_shared = (u16*)take((size_t)EL * 64 * 2);   // ef2a input, then efa fsum
    u16* wt_ninj1 = (u16*)take((size_t)640 * 64 * 2);
    u16* wt_node1 = (u16*)take((size_t)320 * 64 * 2);
    u16* wt_fij1 = (u16*)take((size_t)320 * 32 * 2);
    u16* wt_ninj2a = (u16*)take((size_t)640 * 96 * 2);
    u16* wt_ninj2b = (u16*)take((size_t)640 * 96 * 2);
    u16* wt_fij2a = (u16*)take((size_t)320 * 64 * 2);
    u16* wt_fij2b = (u16*)take((size_t)320 * 64 * 2);
    u16* wt_node2a = (u16*)take((size_t)768 * 96 * 2);
    u16* wt_node2b = (u16*)take((size_t)768 * 96 * 2);
    float* attn_p1 = (float*)take((size_t)320 * 4);
    float* bias_cat1 = (float*)take((size_t)640 * 4);
    float* bias_cat2a = (float*)take((size_t)640 * 4);
    float* bias_cat2b = (float*)take((size_t)640 * 4);
    u16* slab = (u16*)take(((size_t)NG * 640 + (size_t)(EG / 4) * 320) * 2);  // 147.5 MB

    auto cvt = [&](const float* s, u16* d, int M, int K, int Kpad) {
        convert_pad_kernel<<<cdiv(M * Kpad, 256), 256, 0, stream>>>(s, d, M, K, Kpad);
    };
    auto wtr = [&](const float* W, int ldw, u16* d, int K, int N, int Nalloc, int Kpad) {
        wtrans_kernel<<<cdiv(Nalloc * Kpad, 256), 256, 0, stream>>>(W, ldw, d, K, N, Nalloc, Kpad);
    };
    auto build_csr = [&](const int* dst, const int* src, int* row_ptr, int* eidx, int* srcs,
                         int* cnt, int N, int E) {
        hipMemsetAsync(cnt, 0, (size_t)N * 4, stream);
        hist_kernel<<<cdiv(E, 256), 256, 0, stream>>>(dst, cnt, E);
        int nblk = cdiv(N, 1024);
        scan_block_kernel<<<nblk, 1024, 0, stream>>>(cnt, row_ptr, bsum, N);
        scan_top_kernel<<<1, 64, 0, stream>>>(bsum, nblk);
        scan_add_kernel<<<cdiv(N, 256), 256, 0, stream>>>(row_ptr, bsum, N, E);
        hipMemsetAsync(cnt, 0, (size_t)N * 4, stream);
        scatter_kernel<<<cdiv(E, 256), 256, 0, stream>>>(dst, src, row_ptr, cnt, eidx, srcs, E);
    };

    build_csr(gg_dst, gg_src, gg_row, gg_eidx, gg_srcs, gg_cnt, NG, EG);
    build_csr(lg_dst, lg_src, lg_row, lg_eidx, lg_srcs, lg_cnt, NL, EL);

    // prep: conversions + weight transforms + meta
    cvt(gg_nf, gg_nf_bf, NG, 40, 64);
    cvt(gg_ef, gg_ef_bf, EG, 10, 32);
    cvt(lg_nf, lg_nf_bf, NL, 92, 96);
    wtrans_hp_kernel<<<cdiv(320 * 64, 256), 256, 0, stream>>>(W_ni1, 288, wt_ninj1, 40, 64);
    wtrans_hp_kernel<<<cdiv(320 * 64, 256), 256, 0, stream>>>(W_nj1, 288, wt_ninj1 + 320 * 64, 40, 64);
    wtrans_hp_kernel<<<cdiv(320 * 32, 256), 256, 0, stream>>>(W_fij1, 288, wt_fij1, 10, 32);
    wtr(W_node1, 320, wt_node1, 40, 320, 320, 64);
    wtr(W_ni2a, 320, wt_ninj2a, 92, 320, 320, 96);
    wtr(W_nj2a, 320, wt_ninj2a + 320 * 96, 92, 320, 320, 96);
    wtr(W_ni2b, 320, wt_ninj2b, 92, 320, 320, 96);
    wtr(W_nj2b, 320, wt_ninj2b + 320 * 96, 92, 320, 320, 96);
    wtr(W_fij2a, 320, wt_fij2a, 40, 320, 320, 64);
    wtr(W_fij2b, 320, wt_fij2b, 40, 320, 320, 64);
    wtr(W_node2a, 736, wt_node2a, 92, 736, 768, 96);
    wtr(W_node2b, 736, wt_node2b, 92, 736, 768, 96);
    meta_kernel<<<cdiv(2240, 256), 256, 0, stream>>>(attn1, bias1, bias2a, bias2b,
                                                     attn_p1, bias_cat1, bias_cat2a, bias_cat2b);

    // ---------------- stage 1 (gg): single pass, 8 heads (FE padded 36->40) ----------------
    {
        u16* Pn1 = slab;                                  // [NG][640]
        u16* Pe1 = slab + (size_t)NG * 640;               // [EG/4][320] chunk
        gemm_bf_kernel<64><<<dim3(NG / 64, 10), 256, 0, stream>>>(
            gg_nf_bf, wt_ninj1, bias_cat1, Pn1, 640, 640);
        for (int ch = 0; ch < 4; ++ch) {
            const int e0 = ch * (EG / 4);
            gemm_bf_kernel<32><<<dim3((EG / 4) / 64, 5), 256, 0, stream>>>(
                gg_ef_bf + (size_t)e0 * 32, wt_fij1, nullptr, Pe1, 320, 320);
            edge_combine_kernel<1><<<(EG / 4) / 4, 256, 0, stream>>>(
                gg_src, gg_dst, Pn1, Pe1, attn_p1, esc, y22p, e0, EG / 4, NG);
        }
        csr_softmax_kernel<8><<<NG / 4, 256, 0, stream>>>(gg_row, gg_eidx, esc, wcsr, NG);
        u16* Pnode1 = slab;   // alias: Pn1/Pe1 dead
        gemm_bf_kernel<64><<<dim3(NG / 64, 5), 256, 0, stream>>>(
            gg_nf_bf, wt_node1, b_node1, Pnode1, 320, 320);
        node_agg_kernel<40, 8, 0, 320><<<NG / 4, 256, 0, stream>>>(gg_row, gg_srcs, wcsr,
                                                                   Pnode1, y2n, NG);
    }

    // ef for lg layer 2a
    ef2a_kernel<<<cdiv(EL * 64, 256), 256, 0, stream>>>(lg_ef, y2n, ef_shared);

    // ---------------- stage 2 (lg), two layers ----------------
    for (int layer = 0; layer < 2; ++layer) {
        const bool a = (layer == 0);
        const u16* nf_in = a ? lg_nf_bf : nfa_bf;
        const u16* Wninj = a ? wt_ninj2a : wt_ninj2b;
        const u16* Wfij = a ? wt_fij2a : wt_fij2b;
        const u16* Wnode = a ? wt_node2a : wt_node2b;
        const float* bn = a ? b_node2a : b_node2b;
        const float* bcat = a ? bias_cat2a : bias_cat2b;
        const float* at = a ? attn2a : attn2b;
        u16* nf_out = a ? nfa_bf : nfb_bf;

        u16* Pn2 = slab;                                  // [NL][640]
        u16* Pe2 = slab + (size_t)NL * 640;               // [EL][320]
        gemm_bf_kernel<96><<<dim3(NL / 64, 10), 256, 0, stream>>>(nf_in, Wninj, bcat, Pn2, 640, 640);
        gemm_bf_kernel<64><<<dim3(EL / 64, 5), 256, 0, stream>>>(ef_shared, Wfij, nullptr, Pe2, 320, 320);
        if (a)
            edge_combine_kernel<2><<<EL / 4, 256, 0, stream>>>(
                lg_src, lg_dst, Pn2, Pe2, at, esc, ef_shared, 0, EL, EL);
        else
            edge_combine_kernel<0><<<EL / 4, 256, 0, stream>>>(
                lg_src, lg_dst, Pn2, Pe2, at, esc, nullptr, 0, EL, 0);
        csr_softmax_kernel<8><<<NL / 4, 256, 0, stream>>>(lg_row, lg_eidx, esc, wcsr, NL);
        u16* Pnode2 = slab;   // alias: Pn2/Pe2 dead; stride 768 (row 1536B, 128B-aligned)
        gemm_bf_kernel<96><<<dim3(NL / 64, 12), 256, 0, stream>>>(nf_in, Wnode, bn, Pnode2, 736, 768);
        node_agg_kernel<92, 8, 1, 768><<<NL / 4, 256, 0, stream>>>(lg_row, lg_srcs, wcsr,
                                                                   Pnode2, nf_out, NL);
    }

    // ---------------- readout ----------------
    readout_kernel<<<NB, 256, 0, stream>>>(nfb_bf, y22p, Wr1, br1, Wr2, br2, out);
}

// Round 4
// 1015.236 us; speedup vs baseline: 1.1699x; 1.0856x over previous
//
#include <hip/hip_runtime.h>
#include <math.h>

#define NG 76800
#define EG 307200
#define NL 38400
#define EL 153600
#define NB 64
#define NH 8

typedef __attribute__((ext_vector_type(8))) short bf16x8;
typedef __attribute__((ext_vector_type(4))) float f32x4;
typedef unsigned short u16;

__device__ __forceinline__ float sigmoidf(float x) { return 1.f / (1.f + expf(-x)); }
__device__ __forceinline__ u16 f2bf(float x) {
    unsigned u = __float_as_uint(x);
    return (u16)((u + 0x7FFFu + ((u >> 16) & 1u)) >> 16);
}
__device__ __forceinline__ float bf2f(u16 v) { return __uint_as_float(((unsigned)v) << 16); }

// ---------------- fp32 -> padded bf16 [M x Kpad] ----------------
__global__ __launch_bounds__(256) void convert_pad_kernel(const float* __restrict__ src,
                                                          u16* __restrict__ dst,
                                                          int M, int K, int Kpad) {
    int i = blockIdx.x * 256 + threadIdx.x;
    if (i >= M * Kpad) return;
    int m = i / Kpad, k = i - m * Kpad;
    dst[i] = (k < K) ? f2bf(src[(size_t)m * K + k]) : (u16)0;
}

// ---------------- W[K x Nfull] -> bf16 Wt[Nalloc x Kpad] (zero padded) ----------------
__global__ __launch_bounds__(256) void wtrans_kernel(const float* __restrict__ W, int ldw,
                                                     u16* __restrict__ dst,
                                                     int K, int N, int Nalloc, int Kpad) {
    int i = blockIdx.x * 256 + threadIdx.x;
    if (i >= Nalloc * Kpad) return;
    int n = i / Kpad, k = i - n * Kpad;
    dst[i] = (n < N && k < K) ? f2bf(W[(size_t)k * ldw + n]) : (u16)0;
}

// ---------------- head-padded transform: FE 36->40, 8 heads, R=320 rows ----------------
__global__ __launch_bounds__(256) void wtrans_hp_kernel(const float* __restrict__ W, int ldw,
                                                        u16* __restrict__ dst,
                                                        int K, int Kpad) {
    int i = blockIdx.x * 256 + threadIdx.x;
    if (i >= 320 * Kpad) return;
    int n = i / Kpad, k = i - n * Kpad;
    int hh = n / 40, f = n - hh * 40;
    float v = (k < K && f < 36) ? W[(size_t)k * ldw + hh * 36 + f] : 0.f;
    dst[i] = f2bf(v);
}

// ---------------- meta: padded attn1 + concat biases ----------------
__global__ __launch_bounds__(256) void meta_kernel(const float* __restrict__ attn1,
                                                   const float* __restrict__ bias1,
                                                   const float* __restrict__ b2a,
                                                   const float* __restrict__ b2b,
                                                   float* __restrict__ attn_p1,
                                                   float* __restrict__ bias_cat1,
                                                   float* __restrict__ bias_cat2a,
                                                   float* __restrict__ bias_cat2b) {
    int i = blockIdx.x * 256 + threadIdx.x;
    if (i < 320) {
        int hh = i / 40, f = i - hh * 40;
        attn_p1[i] = (f < 36) ? attn1[hh * 36 + f] : 0.f;
    } else if (i < 960) {
        int j = i - 320;
        float v = 0.f;
        if (j < 320) {
            int hh = j / 40, f = j - hh * 40;
            v = (f < 36) ? bias1[hh * 36 + f] : 0.f;
        }
        bias_cat1[j] = v;
    } else if (i < 1600) {
        int j = i - 960;
        bias_cat2a[j] = (j < 320) ? b2a[j] : 0.f;
    } else if (i < 2240) {
        int j = i - 1600;
        bias_cat2b[j] = (j < 320) ? b2b[j] : 0.f;
    }
}

// ---------------- LDS-free bf16 MFMA GEMM, LDS-staged full-line epilogue ----------------
// Staging tile padded [16][72] to break the q-group 8-way bank conflict.
template <int KPAD>
__global__ __launch_bounds__(256) void gemm_bf_kernel(const u16* __restrict__ A,
                                                      const u16* __restrict__ Wt,
                                                      const float* __restrict__ bias,
                                                      u16* __restrict__ C, int Ncols,
                                                      int Nstride) {
    __shared__ u16 st[4][16 * 72];
    const int m0 = blockIdx.x * 64;
    const int n0 = blockIdx.y * 64;
    const int wv = threadIdx.x >> 6;
    const int lane = threadIdx.x & 63;
    const int q = lane >> 4;
    const int mr = lane & 15;

    const u16* Arow = A + (size_t)(m0 + wv * 16 + mr) * KPAD;
    f32x4 acc[4];
#pragma unroll
    for (int t = 0; t < 4; ++t) acc[t] = (f32x4){0.f, 0.f, 0.f, 0.f};

#pragma unroll
    for (int k0 = 0; k0 < KPAD; k0 += 32) {
        bf16x8 af = *(const bf16x8*)(Arow + k0 + q * 8);
#pragma unroll
        for (int t = 0; t < 4; ++t) {
            bf16x8 bv = *(const bf16x8*)(Wt + (size_t)(n0 + t * 16 + mr) * KPAD + k0 + q * 8);
            acc[t] = __builtin_amdgcn_mfma_f32_16x16x32_bf16(af, bv, acc[t], 0, 0, 0);
        }
    }

    u16* myst = st[wv];
#pragma unroll
    for (int t = 0; t < 4; ++t) {
        const int colme = n0 + t * 16 + mr;
        const float bb = (bias && colme < Ncols) ? bias[colme] : 0.f;
#pragma unroll
        for (int r = 0; r < 4; ++r)
            myst[(q * 4 + r) * 72 + t * 16 + mr] = f2bf(acc[t][r]);
    }
    // wave-private region: same-wave LDS ordering via lgkmcnt, no barrier needed
    const int rrow = lane >> 3;        // 0..7
    const int rcol = (lane & 7) * 8;   // 0,8,..,56
    bf16x8 v0 = *(const bf16x8*)(myst + rrow * 72 + rcol);
    bf16x8 v1 = *(const bf16x8*)(myst + (rrow + 8) * 72 + rcol);
    const int gcol = n0 + rcol;
    if (gcol < Ncols) {
        const int grow = m0 + wv * 16 + rrow;
        *(bf16x8*)(C + (size_t)grow * Nstride + gcol) = v0;
        *(bf16x8*)(C + (size_t)(grow + 8) * Nstride + gcol) = v1;
    }
}

// ---------------- ef2a = bf16(lg_ef + repeat(y2n,2)), padded to 64 ----------------
__global__ __launch_bounds__(256) void ef2a_kernel(const float* __restrict__ lg_ef,
                                                   const float* __restrict__ y2n,
                                                   u16* __restrict__ dst) {
    int i = blockIdx.x * 256 + threadIdx.x;
    if (i >= EL * 64) return;
    int e = i >> 6, c = i & 63;
    dst[i] = (c < 40) ? f2bf(lg_ef[(size_t)e * 40 + c] + y2n[(size_t)(e >> 1) * 40 + c]) : (u16)0;
}

// ---------------- FUSED: edge-projection GEMM (-> LDS) + edge combine ----------------
// Block = 64 consecutive edges, 512 threads (8 waves).
// Phase 1: Pe tile [64][320] = A[64][KPAD] @ Wt[320][KPAD]^T via MFMA into LDS.
//          Wave wv: rows (wv&3)*16..+16, col half (wv>>2)*160..+160 (acc[10]).
// Phase 2: each wave processes 8 edges; Pe read from LDS, Pn gathered global.
// FSMODE: 0 none; 1 fp32 out stride 36 (f<36, e<fsumE); 2 bf16 out stride 64.
// NOTE (FSMODE 2): fsum may alias A (ef_shared). Safe: each block reads only
// A rows [m0,m0+64) in phase 1, writes only the same rows in phase 2, with a
// barrier between; blocks touch disjoint row ranges.
template <int KPAD, int FSMODE>
__global__ __launch_bounds__(512) void pe_edge_kernel(
    const u16* __restrict__ A,        // [CH][KPAD] edge features (chunk-local)
    const u16* __restrict__ Wt,       // [320][KPAD]
    const int* __restrict__ src, const int* __restrict__ dst,
    const u16* __restrict__ Pn,       // [N][640]
    const float* __restrict__ attn,   // [320]
    float* __restrict__ esc,          // [E][8]
    void* __restrict__ fsum,
    int e0, int CH, int fsumE) {
    __shared__ u16 pe[64][328];       // padded row: 656B -> q-groups split banks
    const int wv = threadIdx.x >> 6;  // 0..7
    const int lane = threadIdx.x & 63;
    const int q = lane >> 4;
    const int mr = lane & 15;
    const int m0 = blockIdx.x * 64;

    // ---- phase 1: GEMM into LDS ----
    {
        const int rg0 = (wv & 3) * 16;
        const int t0 = (wv >> 2) * 10;
        const u16* Arow = A + (size_t)(m0 + rg0 + mr) * KPAD;
        f32x4 acc[10];
#pragma unroll
        for (int t = 0; t < 10; ++t) acc[t] = (f32x4){0.f, 0.f, 0.f, 0.f};
#pragma unroll
        for (int k0 = 0; k0 < KPAD; k0 += 32) {
            bf16x8 af = *(const bf16x8*)(Arow + k0 + q * 8);
#pragma unroll
            for (int t = 0; t < 10; ++t) {
                bf16x8 bv = *(const bf16x8*)(Wt + (size_t)((t0 + t) * 16 + mr) * KPAD + k0 + q * 8);
                acc[t] = __builtin_amdgcn_mfma_f32_16x16x32_bf16(af, bv, acc[t], 0, 0, 0);
            }
        }
#pragma unroll
        for (int t = 0; t < 10; ++t)
#pragma unroll
            for (int r = 0; r < 4; ++r)
                pe[rg0 + q * 4 + r][(t0 + t) * 16 + mr] = f2bf(acc[t][r]);
    }
    __syncthreads();

    // ---- phase 2: combine, 8 edges per wave ----
    const int lc = (lane < 40) ? lane : 39;
    const int h = lc / 5, o = lc - h * 5;
    const int c = h * 40 + o * 8;
    const bool act = (lane < 40);

    float attn_r[8];
#pragma unroll
    for (int j = 0; j < 8; ++j) attn_r[j] = attn[c + j];

    for (int ei = 0; ei < 8; ++ei) {
        const int row = wv * 8 + ei;
        const int e = e0 + m0 + row;
        const int s = src[e], d = dst[e];
        bf16x8 api = *(const bf16x8*)(Pn + (size_t)s * 640 + c);
        bf16x8 apj = *(const bf16x8*)(Pn + (size_t)d * 640 + 320 + c);
        bf16x8 ape = *(const bf16x8*)(&pe[row][c]);

        float v[8];
        float ehp = 0.f;
#pragma unroll
        for (int j = 0; j < 8; ++j) {
            float x = bf2f((u16)api[j]) + bf2f((u16)apj[j]) + bf2f((u16)ape[j]);
            x = x > 0.f ? x : 0.01f * x;   // leaky_relu(0.01)
            v[j] = x;
            ehp += x * attn_r[j];
        }
        float eh = 0.f;
#pragma unroll
        for (int k = 0; k < 5; ++k) eh += __shfl(ehp, h * 5 + k, 64);
        if (act && o == 0) esc[(size_t)e * 8 + h] = eh;

        if (FSMODE != 0 && e < fsumE) {
#pragma unroll
            for (int m = 4; m >= 1; m >>= 1) {
                const int p = (h ^ m) * 5 + o;
#pragma unroll
                for (int j = 0; j < 8; ++j) v[j] += __shfl(v[j], p, 64);
            }
            if (act && h == 0) {
#pragma unroll
                for (int j = 0; j < 8; ++j) {
                    const int f = o * 8 + j;
                    if (FSMODE == 1) {
                        if (f < 36) ((float*)fsum)[(size_t)e * 36 + f] = v[j];
                    } else {
                        ((u16*)fsum)[(size_t)e * 64 + f] = f2bf(v[j]);
                    }
                }
            }
        }
    }
}

// ---------------- CSR build ----------------
__global__ __launch_bounds__(256) void hist_kernel(const int* __restrict__ dst,
                                                   int* __restrict__ cnt, int E) {
    int i = blockIdx.x * 256 + threadIdx.x;
    if (i < E) atomicAdd(&cnt[dst[i]], 1);
}

__global__ __launch_bounds__(1024) void scan_block_kernel(const int* __restrict__ cnt,
                                                          int* __restrict__ excl,
                                                          int* __restrict__ bsum, int N) {
    __shared__ int sd[1024];
    const int tid = threadIdx.x;
    const int i = blockIdx.x * 1024 + tid;
    int v = (i < N) ? cnt[i] : 0;
    sd[tid] = v;
    __syncthreads();
    for (int off = 1; off < 1024; off <<= 1) {
        int t = (tid >= off) ? sd[tid - off] : 0;
        __syncthreads();
        sd[tid] += t;
        __syncthreads();
    }
    if (i < N) excl[i] = sd[tid] - v;
    if (tid == 1023) bsum[blockIdx.x] = sd[1023];
}

__global__ void scan_top_kernel(int* __restrict__ bsum, int nblk) {
    if (threadIdx.x == 0 && blockIdx.x == 0) {
        int run = 0;
        for (int b = 0; b < nblk; ++b) {
            int t = bsum[b];
            bsum[b] = run;
            run += t;
        }
    }
}

__global__ __launch_bounds__(256) void scan_add_kernel(int* __restrict__ row_ptr,
                                                       const int* __restrict__ bsum,
                                                       int N, int E) {
    int i = blockIdx.x * 256 + threadIdx.x;
    if (i < N) row_ptr[i] += bsum[i >> 10];
    if (i == 0) row_ptr[N] = E;
}

// scatter: eidx (edge id) + srcs_csr (source node ids, CSR order)
__global__ __launch_bounds__(256) void scatter_kernel(const int* __restrict__ dst,
                                                      const int* __restrict__ src,
                                                      const int* __restrict__ row_ptr,
                                                      int* __restrict__ cur,
                                                      int* __restrict__ eidx,
                                                      int* __restrict__ srcs, int E) {
    int i = blockIdx.x * 256 + threadIdx.x;
    if (i < E) {
        int d = dst[i];
        int pos = row_ptr[d] + atomicAdd(&cur[d], 1);
        eidx[pos] = i;
        srcs[pos] = src[i];
    }
}

// ---------------- CSR softmax: scores (edge order) -> weights in CSR order ----------------
template <int GH>
__global__ __launch_bounds__(256) void csr_softmax_kernel(
    const int* __restrict__ row_ptr, const int* __restrict__ eidx,
    const float* __restrict__ esc, float* __restrict__ wcsr, int N) {
    constexpr int NS = 64 / GH;
    const int wid = threadIdx.x >> 6;
    const int lane = threadIdx.x & 63;
    const int nid = blockIdx.x * 4 + wid;
    if (nid >= N) return;
    const int r0 = row_ptr[nid], r1 = row_ptr[nid + 1];
    const int h = lane & (GH - 1);
    const int slot = lane / GH;

    float mx = -1e30f;
    for (int i = r0 + slot; i < r1; i += NS)
        mx = fmaxf(mx, esc[(size_t)eidx[i] * GH + h]);
#pragma unroll
    for (int m = GH; m < 64; m <<= 1) mx = fmaxf(mx, __shfl_xor(mx, m, 64));

    float den = 0.f;
    for (int i = r0 + slot; i < r1; i += NS)
        den += expf(esc[(size_t)eidx[i] * GH + h] - mx);
#pragma unroll
    for (int m = GH; m < 64; m <<= 1) den += __shfl_xor(den, m, 64);
    const float rden = 1.f / den;

    for (int i = r0 + slot; i < r1; i += NS)
        wcsr[(size_t)i * GH + h] = expf(esc[(size_t)eidx[i] * GH + h] - mx) * rden;
}

// ---------------- node aggregation: 4-edge batched gathers for MLP ----------------
// OM 0: fp32 out stride Fn. OM 1: bf16 out stride 96 zero-padded 92..95.
// STR: row stride (elements) of Pnode.
template <int Fn, int GH, int OM, int STR>
__global__ __launch_bounds__(256) void node_agg_kernel(
    const int* __restrict__ row_ptr,
    const int* __restrict__ srcs,     // [E] CSR-ordered source node ids
    const float* __restrict__ wcsr,   // [E, GH] CSR-ordered softmax weights
    const u16* __restrict__ Pnode,    // [N, STR] bf16
    void* __restrict__ outp, int N) {
    constexpr int PAIRS = Fn / 2;     // Fn even: 20 / 46
    const int wid = threadIdx.x >> 6;
    const int lane = threadIdx.x & 63;
    const int nid = blockIdx.x * 4 + wid;
    if (nid >= N) return;
    const int r0 = row_ptr[nid], r1 = row_ptr[nid + 1];
    const int col = 2 * lane;
    const bool act = (lane < PAIRS);

    float a0 = 0.f, a1 = 0.f;
    for (int i = r0; i < r1; i += 4) {
        const u16* prs[4];
        float wv[4][GH];
#pragma unroll
        for (int b = 0; b < 4; ++b) {
            const int ii = (i + b < r1) ? (i + b) : (r1 - 1);
            prs[b] = Pnode + (size_t)srcs[ii] * STR;
            const float live = (i + b < r1) ? 1.f : 0.f;
            const float* wp = wcsr + (size_t)ii * GH;
#pragma unroll
            for (int hh = 0; hh < GH; ++hh) wv[b][hh] = wp[hh] * live;
        }
        if (act) {
            unsigned pv[4][GH];
#pragma unroll
            for (int b = 0; b < 4; ++b)
#pragma unroll
                for (int hh = 0; hh < GH; ++hh)
                    pv[b][hh] = *(const unsigned*)(prs[b] + hh * Fn + col);
#pragma unroll
            for (int b = 0; b < 4; ++b)
#pragma unroll
                for (int hh = 0; hh < GH; ++hh) {
                    a0 += wv[b][hh] * bf2f((u16)(pv[b][hh] & 0xFFFFu));
                    a1 += wv[b][hh] * bf2f((u16)(pv[b][hh] >> 16));
                }
        }
    }
    if (OM == 0) {
        if (act) {
            float* op = (float*)outp + (size_t)nid * Fn + col;
            op[0] = a0;
            op[1] = a1;
        }
    } else {
        unsigned* ob = (unsigned*)((u16*)outp + (size_t)nid * 96);
        if (act) {
            unsigned pk = (unsigned)f2bf(a0) | ((unsigned)f2bf(a1) << 16);
            ob[lane] = pk;
        } else if (lane < 48) {
            ob[lane] = 0u;
        }
    }
}

// ---------------- readout ----------------
__global__ __launch_bounds__(256) void readout_kernel(const u16* __restrict__ nfb,
                                                      const float* __restrict__ y22p,
                                                      const float* __restrict__ Wr1,
                                                      const float* __restrict__ br1,
                                                      const float* __restrict__ Wr2,
                                                      const float* __restrict__ br2,
                                                      float* __restrict__ out) {
    const int b = blockIdx.x;
    const int t = threadIdx.x;
    __shared__ float y[128];
    __shared__ float hh[128];
    __shared__ float red[128];
    if (t < 92) {
        float s = 0.f;
        const u16* base = nfb + (size_t)b * 600 * 96 + t;
        for (int i = 0; i < 600; ++i) s += bf2f(base[(size_t)i * 96]);
        y[t] = s * (1.f / 600.f);
    } else if (t >= 128 && t < 164) {
        int f = t - 128;
        float s = 0.f;
        const float* base = y22p + (size_t)b * 1200 * 36 + f;
        for (int i = 0; i < 1200; ++i) s += base[(size_t)i * 36];
        y[92 + f] = s * (1.f / 1200.f);
    }
    __syncthreads();
    if (t < 128) {
        float s = br1[t];
        for (int c = 0; c < 128; ++c) s += y[c] * Wr1[(size_t)c * 128 + t];
        hh[t] = sigmoidf(s);
    }
    __syncthreads();
    if (t < 128) red[t] = hh[t] * Wr2[t];
    __syncthreads();
    for (int k = 64; k > 0; k >>= 1) {
        if (t < k) red[t] += red[t + k];
        __syncthreads();
    }
    if (t == 0) out[b] = sigmoidf(red[0] + br2[0]);
}

// ---------------- host side ----------------
static inline int cdiv(int a, int b) { return (a + b - 1) / b; }

extern "C" void kernel_launch(void* const* d_in, const int* in_sizes, int n_in,
                              void* d_out, int out_size, void* d_ws, size_t ws_size,
                              hipStream_t stream) {
    const int* gg_src = (const int*)d_in[0];
    const int* gg_dst = (const int*)d_in[1];
    const float* gg_nf = (const float*)d_in[2];
    const float* gg_ef = (const float*)d_in[3];
    const int* lg_src = (const int*)d_in[4];
    const int* lg_dst = (const int*)d_in[5];
    const float* lg_nf = (const float*)d_in[6];
    const float* lg_ef = (const float*)d_in[7];
    const float* W_node1 = (const float*)d_in[8];
    const float* b_node1 = (const float*)d_in[9];
    const float* W_ni1 = (const float*)d_in[10];
    const float* W_nj1 = (const float*)d_in[11];
    const float* W_fij1 = (const float*)d_in[12];
    const float* attn1 = (const float*)d_in[13];
    const float* bias1 = (const float*)d_in[14];
    const float* W_node2a = (const float*)d_in[15];
    const float* b_node2a = (const float*)d_in[16];
    const float* W_ni2a = (const float*)d_in[17];
    const float* W_nj2a = (const float*)d_in[18];
    const float* W_fij2a = (const float*)d_in[19];
    const float* attn2a = (const float*)d_in[20];
    const float* bias2a = (const float*)d_in[21];
    const float* W_node2b = (const float*)d_in[22];
    const float* b_node2b = (const float*)d_in[23];
    const float* W_ni2b = (const float*)d_in[24];
    const float* W_nj2b = (const float*)d_in[25];
    const float* W_fij2b = (const float*)d_in[26];
    const float* attn2b = (const float*)d_in[27];
    const float* bias2b = (const float*)d_in[28];
    const float* Wr1 = (const float*)d_in[29];
    const float* br1 = (const float*)d_in[30];
    const float* Wr2 = (const float*)d_in[31];
    const float* br2 = (const float*)d_in[32];
    float* out = (float*)d_out;

    char* ws = (char*)d_ws;
    size_t off = 0;
    auto take = [&](size_t bytes) {
        size_t o = off;
        off += (bytes + 255) & ~(size_t)255;
        return (void*)(ws + o);
    };
    float* y2n = (float*)take((size_t)NG * 40 * 4);
    float* y22p = (float*)take((size_t)NG * 36 * 4);
    float* esc = (float*)take((size_t)EG * 8 * 4);
    float* wcsr = (float*)take((size_t)EG * 8 * 4);
    int* gg_row = (int*)take((size_t)(NG + 1) * 4);
    int* gg_eidx = (int*)take((size_t)EG * 4);
    int* gg_srcs = (int*)take((size_t)EG * 4);
    int* gg_cnt = (int*)take((size_t)NG * 4);
    int* lg_row = (int*)take((size_t)(NL + 1) * 4);
    int* lg_eidx = (int*)take((size_t)EL * 4);
    int* lg_srcs = (int*)take((size_t)EL * 4);
    int* lg_cnt = (int*)take((size_t)NL * 4);
    int* bsum = (int*)take((size_t)128 * 4);
    u16* gg_nf_bf = (u16*)take((size_t)NG * 64 * 2);
    u16* gg_ef_bf = (u16*)take((size_t)EG * 32 * 2);
    u16* lg_nf_bf = (u16*)take((size_t)NL * 96 * 2);
    u16* nfa_bf = (u16*)take((size_t)NL * 96 * 2);
    u16* nfb_bf = (u16*)take((size_t)NL * 96 * 2);
    u16* ef_shared = (u16*)take((size_t)EL * 64 * 2);   // ef2a input, then efa fsum
    u16* wt_ninj1 = (u16*)take((size_t)640 * 64 * 2);
    u16* wt_node1 = (u16*)take((size_t)320 * 64 * 2);
    u16* wt_fij1 = (u16*)take((size_t)320 * 32 * 2);
    u16* wt_ninj2a = (u16*)take((size_t)640 * 96 * 2);
    u16* wt_ninj2b = (u16*)take((size_t)640 * 96 * 2);
    u16* wt_fij2a = (u16*)take((size_t)320 * 64 * 2);
    u16* wt_fij2b = (u16*)take((size_t)320 * 64 * 2);
    u16* wt_node2a = (u16*)take((size_t)768 * 96 * 2);
    u16* wt_node2b = (u16*)take((size_t)768 * 96 * 2);
    float* attn_p1 = (float*)take((size_t)320 * 4);
    float* bias_cat1 = (float*)take((size_t)640 * 4);
    float* bias_cat2a = (float*)take((size_t)640 * 4);
    float* bias_cat2b = (float*)take((size_t)640 * 4);
    u16* slab = (u16*)take(((size_t)NG * 640 + (size_t)(EG / 4) * 320) * 2);

    auto cvt = [&](const float* s, u16* d, int M, int K, int Kpad) {
        convert_pad_kernel<<<cdiv(M * Kpad, 256), 256, 0, stream>>>(s, d, M, K, Kpad);
    };
    auto wtr = [&](const float* W, int ldw, u16* d, int K, int N, int Nalloc, int Kpad) {
        wtrans_kernel<<<cdiv(Nalloc * Kpad, 256), 256, 0, stream>>>(W, ldw, d, K, N, Nalloc, Kpad);
    };
    auto build_csr = [&](const int* dst, const int* src, int* row_ptr, int* eidx, int* srcs,
                         int* cnt, int N, int E) {
        hipMemsetAsync(cnt, 0, (size_t)N * 4, stream);
        hist_kernel<<<cdiv(E, 256), 256, 0, stream>>>(dst, cnt, E);
        int nblk = cdiv(N, 1024);
        scan_block_kernel<<<nblk, 1024, 0, stream>>>(cnt, row_ptr, bsum, N);
        scan_top_kernel<<<1, 64, 0, stream>>>(bsum, nblk);
        scan_add_kernel<<<cdiv(N, 256), 256, 0, stream>>>(row_ptr, bsum, N, E);
        hipMemsetAsync(cnt, 0, (size_t)N * 4, stream);
        scatter_kernel<<<cdiv(E, 256), 256, 0, stream>>>(dst, src, row_ptr, cnt, eidx, srcs, E);
    };

    build_csr(gg_dst, gg_src, gg_row, gg_eidx, gg_srcs, gg_cnt, NG, EG);
    build_csr(lg_dst, lg_src, lg_row, lg_eidx, lg_srcs, lg_cnt, NL, EL);

    // prep: conversions + weight transforms + meta
    cvt(gg_nf, gg_nf_bf, NG, 40, 64);
    cvt(gg_ef, gg_ef_bf, EG, 10, 32);
    cvt(lg_nf, lg_nf_bf, NL, 92, 96);
    wtrans_hp_kernel<<<cdiv(320 * 64, 256), 256, 0, stream>>>(W_ni1, 288, wt_ninj1, 40, 64);
    wtrans_hp_kernel<<<cdiv(320 * 64, 256), 256, 0, stream>>>(W_nj1, 288, wt_ninj1 + 320 * 64, 40, 64);
    wtrans_hp_kernel<<<cdiv(320 * 32, 256), 256, 0, stream>>>(W_fij1, 288, wt_fij1, 10, 32);
    wtr(W_node1, 320, wt_node1, 40, 320, 320, 64);
    wtr(W_ni2a, 320, wt_ninj2a, 92, 320, 320, 96);
    wtr(W_nj2a, 320, wt_ninj2a + 320 * 96, 92, 320, 320, 96);
    wtr(W_ni2b, 320, wt_ninj2b, 92, 320, 320, 96);
    wtr(W_nj2b, 320, wt_ninj2b + 320 * 96, 92, 320, 320, 96);
    wtr(W_fij2a, 320, wt_fij2a, 40, 320, 320, 64);
    wtr(W_fij2b, 320, wt_fij2b, 40, 320, 320, 64);
    wtr(W_node2a, 736, wt_node2a, 92, 736, 768, 96);
    wtr(W_node2b, 736, wt_node2b, 92, 736, 768, 96);
    meta_kernel<<<cdiv(2240, 256), 256, 0, stream>>>(attn1, bias1, bias2a, bias2b,
                                                     attn_p1, bias_cat1, bias_cat2a, bias_cat2b);

    // ---------------- stage 1 (gg): fused Pe-GEMM + edge combine ----------------
    {
        u16* Pn1 = slab;                                  // [NG][640]
        gemm_bf_kernel<64><<<dim3(NG / 64, 10), 256, 0, stream>>>(
            gg_nf_bf, wt_ninj1, bias_cat1, Pn1, 640, 640);
        for (int ch = 0; ch < 4; ++ch) {
            const int e0 = ch * (EG / 4);
            pe_edge_kernel<32, 1><<<(EG / 4) / 64, 512, 0, stream>>>(
                gg_ef_bf + (size_t)e0 * 32, wt_fij1, gg_src, gg_dst, Pn1,
                attn_p1, esc, y22p, e0, EG / 4, NG);
        }
        csr_softmax_kernel<8><<<NG / 4, 256, 0, stream>>>(gg_row, gg_eidx, esc, wcsr, NG);
        u16* Pnode1 = slab;   // alias: Pn1 dead
        gemm_bf_kernel<64><<<dim3(NG / 64, 5), 256, 0, stream>>>(
            gg_nf_bf, wt_node1, b_node1, Pnode1, 320, 320);
        node_agg_kernel<40, 8, 0, 320><<<NG / 4, 256, 0, stream>>>(gg_row, gg_srcs, wcsr,
                                                                   Pnode1, y2n, NG);
    }

    // ef for lg layer 2a
    ef2a_kernel<<<cdiv(EL * 64, 256), 256, 0, stream>>>(lg_ef, y2n, ef_shared);

    // ---------------- stage 2 (lg), two layers ----------------
    for (int layer = 0; layer < 2; ++layer) {
        const bool a = (layer == 0);
        const u16* nf_in = a ? lg_nf_bf : nfa_bf;
        const u16* Wninj = a ? wt_ninj2a : wt_ninj2b;
        const u16* Wfij = a ? wt_fij2a : wt_fij2b;
        const u16* Wnode = a ? wt_node2a : wt_node2b;
        const float* bn = a ? b_node2a : b_node2b;
        const float* bcat = a ? bias_cat2a : bias_cat2b;
        const float* at = a ? attn2a : attn2b;
        u16* nf_out = a ? nfa_bf : nfb_bf;

        u16* Pn2 = slab;                                  // [NL][640]
        gemm_bf_kernel<96><<<dim3(NL / 64, 10), 256, 0, stream>>>(nf_in, Wninj, bcat, Pn2, 640, 640);
        if (a)
            pe_edge_kernel<64, 2><<<EL / 64, 512, 0, stream>>>(
                ef_shared, Wfij, lg_src, lg_dst, Pn2, at, esc, ef_shared, 0, EL, EL);
        else
            pe_edge_kernel<64, 0><<<EL / 64, 512, 0, stream>>>(
                ef_shared, Wfij, lg_src, lg_dst, Pn2, at, esc, nullptr, 0, EL, 0);
        csr_softmax_kernel<8><<<NL / 4, 256, 0, stream>>>(lg_row, lg_eidx, esc, wcsr, NL);
        u16* Pnode2 = slab;   // alias: Pn2 dead; stride 768 (row 1536B, 128B-aligned)
        gemm_bf_kernel<96><<<dim3(NL / 64, 12), 256, 0, stream>>>(nf_in, Wnode, bn, Pnode2, 736, 768);
        node_agg_kernel<92, 8, 1, 768><<<NL / 4, 256, 0, stream>>>(lg_row, lg_srcs, wcsr,
                                                                   Pnode2, nf_out, NL);
    }

    // ---------------- readout ----------------
    readout_kernel<<<NB, 256, 0, stream>>>(nfb_bf, y22p, Wr1, br1, Wr2, br2, out);
}

// Round 5
// 980.529 us; speedup vs baseline: 1.2113x; 1.0354x over previous
//
#include <hip/hip_runtime.h>
#include <math.h>

#define NG 76800
#define EG 307200
#define NL 38400
#define EL 153600
#define NB 64
#define NH 8

typedef __attribute__((ext_vector_type(8))) short bf16x8;
typedef __attribute__((ext_vector_type(4))) float f32x4;
typedef unsigned short u16;

__device__ __forceinline__ float sigmoidf(float x) { return 1.f / (1.f + expf(-x)); }
__device__ __forceinline__ u16 f2bf(float x) {
    unsigned u = __float_as_uint(x);
    return (u16)((u + 0x7FFFu + ((u >> 16) & 1u)) >> 16);
}
__device__ __forceinline__ float bf2f(u16 v) { return __uint_as_float(((unsigned)v) << 16); }

// ---------------- fp32 -> padded bf16 [M x Kpad] ----------------
__global__ __launch_bounds__(256) void convert_pad_kernel(const float* __restrict__ src,
                                                          u16* __restrict__ dst,
                                                          int M, int K, int Kpad) {
    int i = blockIdx.x * 256 + threadIdx.x;
    if (i >= M * Kpad) return;
    int m = i / Kpad, k = i - m * Kpad;
    dst[i] = (k < K) ? f2bf(src[(size_t)m * K + k]) : (u16)0;
}

// ---------------- W[K x Nfull] -> bf16 Wt[Nalloc x Kpad] (zero padded) ----------------
__global__ __launch_bounds__(256) void wtrans_kernel(const float* __restrict__ W, int ldw,
                                                     u16* __restrict__ dst,
                                                     int K, int N, int Nalloc, int Kpad) {
    int i = blockIdx.x * 256 + threadIdx.x;
    if (i >= Nalloc * Kpad) return;
    int n = i / Kpad, k = i - n * Kpad;
    dst[i] = (n < N && k < K) ? f2bf(W[(size_t)k * ldw + n]) : (u16)0;
}

// ---------------- head-padded transform: FE 36->40, 8 heads, R=320 rows ----------------
__global__ __launch_bounds__(256) void wtrans_hp_kernel(const float* __restrict__ W, int ldw,
                                                        u16* __restrict__ dst,
                                                        int K, int Kpad) {
    int i = blockIdx.x * 256 + threadIdx.x;
    if (i >= 320 * Kpad) return;
    int n = i / Kpad, k = i - n * Kpad;
    int hh = n / 40, f = n - hh * 40;
    float v = (k < K && f < 36) ? W[(size_t)k * ldw + hh * 36 + f] : 0.f;
    dst[i] = f2bf(v);
}

// ---------------- meta: padded attn1 + concat biases ----------------
__global__ __launch_bounds__(256) void meta_kernel(const float* __restrict__ attn1,
                                                   const float* __restrict__ bias1,
                                                   const float* __restrict__ b2a,
                                                   const float* __restrict__ b2b,
                                                   float* __restrict__ attn_p1,
                                                   float* __restrict__ bias_cat1,
                                                   float* __restrict__ bias_cat2a,
                                                   float* __restrict__ bias_cat2b) {
    int i = blockIdx.x * 256 + threadIdx.x;
    if (i < 320) {
        int hh = i / 40, f = i - hh * 40;
        attn_p1[i] = (f < 36) ? attn1[hh * 36 + f] : 0.f;
    } else if (i < 960) {
        int j = i - 320;
        float v = 0.f;
        if (j < 320) {
            int hh = j / 40, f = j - hh * 40;
            v = (f < 36) ? bias1[hh * 36 + f] : 0.f;
        }
        bias_cat1[j] = v;
    } else if (i < 1600) {
        int j = i - 960;
        bias_cat2a[j] = (j < 320) ? b2a[j] : 0.f;
    } else if (i < 2240) {
        int j = i - 1600;
        bias_cat2b[j] = (j < 320) ? b2b[j] : 0.f;
    }
}

// ---------------- LDS-free bf16 MFMA GEMM, LDS-staged full-line epilogue ----------------
// Staging tile padded [16][72] to break the q-group 8-way bank conflict.
template <int KPAD>
__global__ __launch_bounds__(256) void gemm_bf_kernel(const u16* __restrict__ A,
                                                      const u16* __restrict__ Wt,
                                                      const float* __restrict__ bias,
                                                      u16* __restrict__ C, int Ncols,
                                                      int Nstride) {
    __shared__ u16 st[4][16 * 72];
    const int m0 = blockIdx.x * 64;
    const int n0 = blockIdx.y * 64;
    const int wv = threadIdx.x >> 6;
    const int lane = threadIdx.x & 63;
    const int q = lane >> 4;
    const int mr = lane & 15;

    const u16* Arow = A + (size_t)(m0 + wv * 16 + mr) * KPAD;
    f32x4 acc[4];
#pragma unroll
    for (int t = 0; t < 4; ++t) acc[t] = (f32x4){0.f, 0.f, 0.f, 0.f};

#pragma unroll
    for (int k0 = 0; k0 < KPAD; k0 += 32) {
        bf16x8 af = *(const bf16x8*)(Arow + k0 + q * 8);
#pragma unroll
        for (int t = 0; t < 4; ++t) {
            bf16x8 bv = *(const bf16x8*)(Wt + (size_t)(n0 + t * 16 + mr) * KPAD + k0 + q * 8);
            acc[t] = __builtin_amdgcn_mfma_f32_16x16x32_bf16(af, bv, acc[t], 0, 0, 0);
        }
    }

    u16* myst = st[wv];
#pragma unroll
    for (int t = 0; t < 4; ++t) {
        const int colme = n0 + t * 16 + mr;
        const float bb = (bias && colme < Ncols) ? bias[colme] : 0.f;
#pragma unroll
        for (int r = 0; r < 4; ++r)
            myst[(q * 4 + r) * 72 + t * 16 + mr] = f2bf(acc[t][r] + bb);
    }
    // wave-private region: same-wave LDS ordering via lgkmcnt, no barrier needed
    const int rrow = lane >> 3;        // 0..7
    const int rcol = (lane & 7) * 8;   // 0,8,..,56
    bf16x8 v0 = *(const bf16x8*)(myst + rrow * 72 + rcol);
    bf16x8 v1 = *(const bf16x8*)(myst + (rrow + 8) * 72 + rcol);
    const int gcol = n0 + rcol;
    if (gcol < Ncols) {
        const int grow = m0 + wv * 16 + rrow;
        *(bf16x8*)(C + (size_t)grow * Nstride + gcol) = v0;
        *(bf16x8*)(C + (size_t)(grow + 8) * Nstride + gcol) = v1;
    }
}

// ---------------- ef2a = bf16(lg_ef + repeat(y2n,2)), padded to 64 ----------------
__global__ __launch_bounds__(256) void ef2a_kernel(const float* __restrict__ lg_ef,
                                                   const float* __restrict__ y2n,
                                                   u16* __restrict__ dst) {
    int i = blockIdx.x * 256 + threadIdx.x;
    if (i >= EL * 64) return;
    int e = i >> 6, c = i & 63;
    dst[i] = (c < 40) ? f2bf(lg_ef[(size_t)e * 40 + c] + y2n[(size_t)(e >> 1) * 40 + c]) : (u16)0;
}

// ---------------- FUSED: edge-projection GEMM (-> LDS) + edge combine ----------------
// Block = 32 consecutive edges, 256 threads (4 waves). LDS 21KB -> 7 blocks/CU.
// Phase 1: Pe tile [32][320] = A[32][KPAD] @ Wt[320][KPAD]^T via MFMA into LDS.
//          Wave wv: rows (wv&1)*16..+16, col half (wv>>1)*160..+160 (acc[10]).
// Phase 2: each wave processes 8 edges with 1-deep prefetch of the next edge's
//          Pn gathers (2 extra 640B loads in flight per wave).
// FSMODE: 0 none; 1 fp32 out stride 36 (f<36, e<fsumE); 2 bf16 out stride 64.
// NOTE (FSMODE 2): fsum may alias A (ef_shared). Safe: each block reads only
// its own A rows in phase 1 and writes only the same rows in phase 2, with a
// barrier between; blocks touch disjoint row ranges.
template <int KPAD, int FSMODE>
__global__ __launch_bounds__(256) void pe_edge_kernel(
    const u16* __restrict__ A,        // [CH][KPAD] edge features
    const u16* __restrict__ Wt,       // [320][KPAD]
    const int* __restrict__ src, const int* __restrict__ dst,
    const u16* __restrict__ Pn,       // [N][640]
    const float* __restrict__ attn,   // [320]
    float* __restrict__ esc,          // [E][8]
    void* __restrict__ fsum,
    int e0, int CH, int fsumE) {
    __shared__ u16 pe[32][328];       // padded row pitch 656B
    const int wv = threadIdx.x >> 6;  // 0..3
    const int lane = threadIdx.x & 63;
    const int q = lane >> 4;
    const int mr = lane & 15;
    const int m0 = blockIdx.x * 32;

    // ---- phase 1: GEMM into LDS ----
    {
        const int rg0 = (wv & 1) * 16;
        const int t0 = (wv >> 1) * 10;
        const u16* Arow = A + (size_t)(m0 + rg0 + mr) * KPAD;
        f32x4 acc[10];
#pragma unroll
        for (int t = 0; t < 10; ++t) acc[t] = (f32x4){0.f, 0.f, 0.f, 0.f};
#pragma unroll
        for (int k0 = 0; k0 < KPAD; k0 += 32) {
            bf16x8 af = *(const bf16x8*)(Arow + k0 + q * 8);
#pragma unroll
            for (int t = 0; t < 10; ++t) {
                bf16x8 bv = *(const bf16x8*)(Wt + (size_t)((t0 + t) * 16 + mr) * KPAD + k0 + q * 8);
                acc[t] = __builtin_amdgcn_mfma_f32_16x16x32_bf16(af, bv, acc[t], 0, 0, 0);
            }
        }
#pragma unroll
        for (int t = 0; t < 10; ++t)
#pragma unroll
            for (int r = 0; r < 4; ++r)
                pe[rg0 + q * 4 + r][(t0 + t) * 16 + mr] = f2bf(acc[t][r]);
    }
    __syncthreads();

    // ---- phase 2: combine, 8 edges per wave, 1-deep prefetch ----
    const int lc = (lane < 40) ? lane : 39;
    const int h = lc / 5, o = lc - h * 5;
    const int c = h * 40 + o * 8;
    const bool act = (lane < 40);

    float attn_r[8];
#pragma unroll
    for (int j = 0; j < 8; ++j) attn_r[j] = attn[c + j];

    const int row0 = wv * 8;
    int e = e0 + m0 + row0;
    int s = src[e], d = dst[e];
    bf16x8 api = *(const bf16x8*)(Pn + (size_t)s * 640 + c);
    bf16x8 apj = *(const bf16x8*)(Pn + (size_t)d * 640 + 320 + c);

#pragma unroll
    for (int ei = 0; ei < 8; ++ei) {
        bf16x8 napi, napj;
        if (ei < 7) {
            const int ne = e + 1;
            const int ns = src[ne], nd = dst[ne];
            napi = *(const bf16x8*)(Pn + (size_t)ns * 640 + c);
            napj = *(const bf16x8*)(Pn + (size_t)nd * 640 + 320 + c);
        }
        const int row = row0 + ei;
        bf16x8 ape = *(const bf16x8*)(&pe[row][c]);

        float v[8];
        float ehp = 0.f;
#pragma unroll
        for (int j = 0; j < 8; ++j) {
            float x = bf2f((u16)api[j]) + bf2f((u16)apj[j]) + bf2f((u16)ape[j]);
            x = x > 0.f ? x : 0.01f * x;   // leaky_relu(0.01)
            v[j] = x;
            ehp += x * attn_r[j];
        }
        float eh = 0.f;
#pragma unroll
        for (int k = 0; k < 5; ++k) eh += __shfl(ehp, h * 5 + k, 64);
        if (act && o == 0) esc[(size_t)e * 8 + h] = eh;

        if (FSMODE != 0 && e < fsumE) {
#pragma unroll
            for (int m = 4; m >= 1; m >>= 1) {
                const int p = (h ^ m) * 5 + o;
#pragma unroll
                for (int j = 0; j < 8; ++j) v[j] += __shfl(v[j], p, 64);
            }
            if (act && h == 0) {
#pragma unroll
                for (int j = 0; j < 8; ++j) {
                    const int f = o * 8 + j;
                    if (FSMODE == 1) {
                        if (f < 36) ((float*)fsum)[(size_t)e * 36 + f] = v[j];
                    } else {
                        ((u16*)fsum)[(size_t)e * 64 + f] = f2bf(v[j]);
                    }
                }
            }
        }
        if (ei < 7) {
            api = napi;
            apj = napj;
        }
        ++e;
    }
}

// ---------------- CSR build ----------------
__global__ __launch_bounds__(256) void hist_kernel(const int* __restrict__ dst,
                                                   int* __restrict__ cnt, int E) {
    int i = blockIdx.x * 256 + threadIdx.x;
    if (i < E) atomicAdd(&cnt[dst[i]], 1);
}

__global__ __launch_bounds__(1024) void scan_block_kernel(const int* __restrict__ cnt,
                                                          int* __restrict__ excl,
                                                          int* __restrict__ bsum, int N) {
    __shared__ int sd[1024];
    const int tid = threadIdx.x;
    const int i = blockIdx.x * 1024 + tid;
    int v = (i < N) ? cnt[i] : 0;
    sd[tid] = v;
    __syncthreads();
    for (int off = 1; off < 1024; off <<= 1) {
        int t = (tid >= off) ? sd[tid - off] : 0;
        __syncthreads();
        sd[tid] += t;
        __syncthreads();
    }
    if (i < N) excl[i] = sd[tid] - v;
    if (tid == 1023) bsum[blockIdx.x] = sd[1023];
}

__global__ void scan_top_kernel(int* __restrict__ bsum, int nblk) {
    if (threadIdx.x == 0 && blockIdx.x == 0) {
        int run = 0;
        for (int b = 0; b < nblk; ++b) {
            int t = bsum[b];
            bsum[b] = run;
            run += t;
        }
    }
}

__global__ __launch_bounds__(256) void scan_add_kernel(int* __restrict__ row_ptr,
                                                       const int* __restrict__ bsum,
                                                       int N, int E) {
    int i = blockIdx.x * 256 + threadIdx.x;
    if (i < N) row_ptr[i] += bsum[i >> 10];
    if (i == 0) row_ptr[N] = E;
}

// scatter: eidx (edge id) + srcs_csr (source node ids, CSR order)
__global__ __launch_bounds__(256) void scatter_kernel(const int* __restrict__ dst,
                                                      const int* __restrict__ src,
                                                      const int* __restrict__ row_ptr,
                                                      int* __restrict__ cur,
                                                      int* __restrict__ eidx,
                                                      int* __restrict__ srcs, int E) {
    int i = blockIdx.x * 256 + threadIdx.x;
    if (i < E) {
        int d = dst[i];
        int pos = row_ptr[d] + atomicAdd(&cur[d], 1);
        eidx[pos] = i;
        srcs[pos] = src[i];
    }
}

// ---------------- CSR softmax: scores (edge order) -> weights in CSR order ----------------
template <int GH>
__global__ __launch_bounds__(256) void csr_softmax_kernel(
    const int* __restrict__ row_ptr, const int* __restrict__ eidx,
    const float* __restrict__ esc, float* __restrict__ wcsr, int N) {
    constexpr int NS = 64 / GH;
    const int wid = threadIdx.x >> 6;
    const int lane = threadIdx.x & 63;
    const int nid = blockIdx.x * 4 + wid;
    if (nid >= N) return;
    const int r0 = row_ptr[nid], r1 = row_ptr[nid + 1];
    const int h = lane & (GH - 1);
    const int slot = lane / GH;

    float mx = -1e30f;
    for (int i = r0 + slot; i < r1; i += NS)
        mx = fmaxf(mx, esc[(size_t)eidx[i] * GH + h]);
#pragma unroll
    for (int m = GH; m < 64; m <<= 1) mx = fmaxf(mx, __shfl_xor(mx, m, 64));

    float den = 0.f;
    for (int i = r0 + slot; i < r1; i += NS)
        den += expf(esc[(size_t)eidx[i] * GH + h] - mx);
#pragma unroll
    for (int m = GH; m < 64; m <<= 1) den += __shfl_xor(den, m, 64);
    const float rden = 1.f / den;

    for (int i = r0 + slot; i < r1; i += NS)
        wcsr[(size_t)i * GH + h] = expf(esc[(size_t)eidx[i] * GH + h] - mx) * rden;
}

// ---------------- node aggregation: 4-edge batched gathers for MLP ----------------
// OM 0: fp32 out stride Fn. OM 1: bf16 out stride 96 zero-padded 92..95.
// STR: row stride (elements) of Pnode.
template <int Fn, int GH, int OM, int STR>
__global__ __launch_bounds__(256) void node_agg_kernel(
    const int* __restrict__ row_ptr,
    const int* __restrict__ srcs,     // [E] CSR-ordered source node ids
    const float* __restrict__ wcsr,   // [E, GH] CSR-ordered softmax weights
    const u16* __restrict__ Pnode,    // [N, STR] bf16
    void* __restrict__ outp, int N) {
    constexpr int PAIRS = Fn / 2;     // Fn even: 20 / 46
    const int wid = threadIdx.x >> 6;
    const int lane = threadIdx.x & 63;
    const int nid = blockIdx.x * 4 + wid;
    if (nid >= N) return;
    const int r0 = row_ptr[nid], r1 = row_ptr[nid + 1];
    const int col = 2 * lane;
    const bool act = (lane < PAIRS);

    float a0 = 0.f, a1 = 0.f;
    for (int i = r0; i < r1; i += 4) {
        const u16* prs[4];
        float wv[4][GH];
#pragma unroll
        for (int b = 0; b < 4; ++b) {
            const int ii = (i + b < r1) ? (i + b) : (r1 - 1);
            prs[b] = Pnode + (size_t)srcs[ii] * STR;
            const float live = (i + b < r1) ? 1.f : 0.f;
            const float* wp = wcsr + (size_t)ii * GH;
#pragma unroll
            for (int hh = 0; hh < GH; ++hh) wv[b][hh] = wp[hh] * live;
        }
        if (act) {
            unsigned pv[4][GH];
#pragma unroll
            for (int b = 0; b < 4; ++b)
#pragma unroll
                for (int hh = 0; hh < GH; ++hh)
                    pv[b][hh] = *(const unsigned*)(prs[b] + hh * Fn + col);
#pragma unroll
            for (int b = 0; b < 4; ++b)
#pragma unroll
                for (int hh = 0; hh < GH; ++hh) {
                    a0 += wv[b][hh] * bf2f((u16)(pv[b][hh] & 0xFFFFu));
                    a1 += wv[b][hh] * bf2f((u16)(pv[b][hh] >> 16));
                }
        }
    }
    if (OM == 0) {
        if (act) {
            float* op = (float*)outp + (size_t)nid * Fn + col;
            op[0] = a0;
            op[1] = a1;
        }
    } else {
        unsigned* ob = (unsigned*)((u16*)outp + (size_t)nid * 96);
        if (act) {
            unsigned pk = (unsigned)f2bf(a0) | ((unsigned)f2bf(a1) << 16);
            ob[lane] = pk;
        } else if (lane < 48) {
            ob[lane] = 0u;
        }
    }
}

// ---------------- readout ----------------
__global__ __launch_bounds__(256) void readout_kernel(const u16* __restrict__ nfb,
                                                      const float* __restrict__ y22p,
                                                      const float* __restrict__ Wr1,
                                                      const float* __restrict__ br1,
                                                      const float* __restrict__ Wr2,
                                                      const float* __restrict__ br2,
                                                      float* __restrict__ out) {
    const int b = blockIdx.x;
    const int t = threadIdx.x;
    __shared__ float y[128];
    __shared__ float hh[128];
    __shared__ float red[128];
    if (t < 92) {
        float s = 0.f;
        const u16* base = nfb + (size_t)b * 600 * 96 + t;
        for (int i = 0; i < 600; ++i) s += bf2f(base[(size_t)i * 96]);
        y[t] = s * (1.f / 600.f);
    } else if (t >= 128 && t < 164) {
        int f = t - 128;
        float s = 0.f;
        const float* base = y22p + (size_t)b * 1200 * 36 + f;
        for (int i = 0; i < 1200; ++i) s += base[(size_t)i * 36];
        y[92 + f] = s * (1.f / 1200.f);
    }
    __syncthreads();
    if (t < 128) {
        float s = br1[t];
        for (int c = 0; c < 128; ++c) s += y[c] * Wr1[(size_t)c * 128 + t];
        hh[t] = sigmoidf(s);
    }
    __syncthreads();
    if (t < 128) red[t] = hh[t] * Wr2[t];
    __syncthreads();
    for (int k = 64; k > 0; k >>= 1) {
        if (t < k) red[t] += red[t + k];
        __syncthreads();
    }
    if (t == 0) out[b] = sigmoidf(red[0] + br2[0]);
}

// ---------------- host side ----------------
static inline int cdiv(int a, int b) { return (a + b - 1) / b; }

extern "C" void kernel_launch(void* const* d_in, const int* in_sizes, int n_in,
                              void* d_out, int out_size, void* d_ws, size_t ws_size,
                              hipStream_t stream) {
    const int* gg_src = (const int*)d_in[0];
    const int* gg_dst = (const int*)d_in[1];
    const float* gg_nf = (const float*)d_in[2];
    const float* gg_ef = (const float*)d_in[3];
    const int* lg_src = (const int*)d_in[4];
    const int* lg_dst = (const int*)d_in[5];
    const float* lg_nf = (const float*)d_in[6];
    const float* lg_ef = (const float*)d_in[7];
    const float* W_node1 = (const float*)d_in[8];
    const float* b_node1 = (const float*)d_in[9];
    const float* W_ni1 = (const float*)d_in[10];
    const float* W_nj1 = (const float*)d_in[11];
    const float* W_fij1 = (const float*)d_in[12];
    const float* attn1 = (const float*)d_in[13];
    const float* bias1 = (const float*)d_in[14];
    const float* W_node2a = (const float*)d_in[15];
    const float* b_node2a = (const float*)d_in[16];
    const float* W_ni2a = (const float*)d_in[17];
    const float* W_nj2a = (const float*)d_in[18];
    const float* W_fij2a = (const float*)d_in[19];
    const float* attn2a = (const float*)d_in[20];
    const float* bias2a = (const float*)d_in[21];
    const float* W_node2b = (const float*)d_in[22];
    const float* b_node2b = (const float*)d_in[23];
    const float* W_ni2b = (const float*)d_in[24];
    const float* W_nj2b = (const float*)d_in[25];
    const float* W_fij2b = (const float*)d_in[26];
    const float* attn2b = (const float*)d_in[27];
    const float* bias2b = (const float*)d_in[28];
    const float* Wr1 = (const float*)d_in[29];
    const float* br1 = (const float*)d_in[30];
    const float* Wr2 = (const float*)d_in[31];
    const float* br2 = (const float*)d_in[32];
    float* out = (float*)d_out;

    char* ws = (char*)d_ws;
    size_t off = 0;
    auto take = [&](size_t bytes) {
        size_t o = off;
        off += (bytes + 255) & ~(size_t)255;
        return (void*)(ws + o);
    };
    float* y2n = (float*)take((size_t)NG * 40 * 4);
    float* y22p = (float*)take((size_t)NG * 36 * 4);
    float* esc = (float*)take((size_t)EG * 8 * 4);
    float* wcsr = (float*)take((size_t)EG * 8 * 4);
    int* gg_row = (int*)take((size_t)(NG + 1) * 4);
    int* gg_eidx = (int*)take((size_t)EG * 4);
    int* gg_srcs = (int*)take((size_t)EG * 4);
    int* gg_cnt = (int*)take((size_t)NG * 4);
    int* lg_row = (int*)take((size_t)(NL + 1) * 4);
    int* lg_eidx = (int*)take((size_t)EL * 4);
    int* lg_srcs = (int*)take((size_t)EL * 4);
    int* lg_cnt = (int*)take((size_t)NL * 4);
    int* bsum = (int*)take((size_t)128 * 4);
    u16* gg_nf_bf = (u16*)take((size_t)NG * 64 * 2);
    u16* gg_ef_bf = (u16*)take((size_t)EG * 32 * 2);
    u16* lg_nf_bf = (u16*)take((size_t)NL * 96 * 2);
    u16* nfa_bf = (u16*)take((size_t)NL * 96 * 2);
    u16* nfb_bf = (u16*)take((size_t)NL * 96 * 2);
    u16* ef_shared = (u16*)take((size_t)EL * 64 * 2);   // ef2a input, then efa fsum
    u16* wt_ninj1 = (u16*)take((size_t)640 * 64 * 2);
    u16* wt_node1 = (u16*)take((size_t)320 * 64 * 2);
    u16* wt_fij1 = (u16*)take((size_t)320 * 32 * 2);
    u16* wt_ninj2a = (u16*)take((size_t)640 * 96 * 2);
    u16* wt_ninj2b = (u16*)take((size_t)640 * 96 * 2);
    u16* wt_fij2a = (u16*)take((size_t)320 * 64 * 2);
    u16* wt_fij2b = (u16*)take((size_t)320 * 64 * 2);
    u16* wt_node2a = (u16*)take((size_t)768 * 96 * 2);
    u16* wt_node2b = (u16*)take((size_t)768 * 96 * 2);
    float* attn_p1 = (float*)take((size_t)320 * 4);
    float* bias_cat1 = (float*)take((size_t)640 * 4);
    float* bias_cat2a = (float*)take((size_t)640 * 4);
    float* bias_cat2b = (float*)take((size_t)640 * 4);
    u16* slab = (u16*)take((size_t)NG * 640 * 2);   // Pn1 / Pn2 / Pnode slabs

    auto cvt = [&](const float* s, u16* d, int M, int K, int Kpad) {
        convert_pad_kernel<<<cdiv(M * Kpad, 256), 256, 0, stream>>>(s, d, M, K, Kpad);
    };
    auto wtr = [&](const float* W, int ldw, u16* d, int K, int N, int Nalloc, int Kpad) {
        wtrans_kernel<<<cdiv(Nalloc * Kpad, 256), 256, 0, stream>>>(W, ldw, d, K, N, Nalloc, Kpad);
    };
    auto build_csr = [&](const int* dst, const int* src, int* row_ptr, int* eidx, int* srcs,
                         int* cnt, int N, int E) {
        hipMemsetAsync(cnt, 0, (size_t)N * 4, stream);
        hist_kernel<<<cdiv(E, 256), 256, 0, stream>>>(dst, cnt, E);
        int nblk = cdiv(N, 1024);
        scan_block_kernel<<<nblk, 1024, 0, stream>>>(cnt, row_ptr, bsum, N);
        scan_top_kernel<<<1, 64, 0, stream>>>(bsum, nblk);
        scan_add_kernel<<<cdiv(N, 256), 256, 0, stream>>>(row_ptr, bsum, N, E);
        hipMemsetAsync(cnt, 0, (size_t)N * 4, stream);
        scatter_kernel<<<cdiv(E, 256), 256, 0, stream>>>(dst, src, row_ptr, cnt, eidx, srcs, E);
    };

    build_csr(gg_dst, gg_src, gg_row, gg_eidx, gg_srcs, gg_cnt, NG, EG);
    build_csr(lg_dst, lg_src, lg_row, lg_eidx, lg_srcs, lg_cnt, NL, EL);

    // prep: conversions + weight transforms + meta
    cvt(gg_nf, gg_nf_bf, NG, 40, 64);
    cvt(gg_ef, gg_ef_bf, EG, 10, 32);
    cvt(lg_nf, lg_nf_bf, NL, 92, 96);
    wtrans_hp_kernel<<<cdiv(320 * 64, 256), 256, 0, stream>>>(W_ni1, 288, wt_ninj1, 40, 64);
    wtrans_hp_kernel<<<cdiv(320 * 64, 256), 256, 0, stream>>>(W_nj1, 288, wt_ninj1 + 320 * 64, 40, 64);
    wtrans_hp_kernel<<<cdiv(320 * 32, 256), 256, 0, stream>>>(W_fij1, 288, wt_fij1, 10, 32);
    wtr(W_node1, 320, wt_node1, 40, 320, 320, 64);
    wtr(W_ni2a, 320, wt_ninj2a, 92, 320, 320, 96);
    wtr(W_nj2a, 320, wt_ninj2a + 320 * 96, 92, 320, 320, 96);
    wtr(W_ni2b, 320, wt_ninj2b, 92, 320, 320, 96);
    wtr(W_nj2b, 320, wt_ninj2b + 320 * 96, 92, 320, 320, 96);
    wtr(W_fij2a, 320, wt_fij2a, 40, 320, 320, 64);
    wtr(W_fij2b, 320, wt_fij2b, 40, 320, 320, 64);
    wtr(W_node2a, 736, wt_node2a, 92, 736, 768, 96);
    wtr(W_node2b, 736, wt_node2b, 92, 736, 768, 96);
    meta_kernel<<<cdiv(2240, 256), 256, 0, stream>>>(attn1, bias1, bias2a, bias2b,
                                                     attn_p1, bias_cat1, bias_cat2a, bias_cat2b);

    // ---------------- stage 1 (gg): fused Pe-GEMM + edge combine, single pass ----------------
    {
        u16* Pn1 = slab;                                  // [NG][640]
        gemm_bf_kernel<64><<<dim3(NG / 64, 10), 256, 0, stream>>>(
            gg_nf_bf, wt_ninj1, bias_cat1, Pn1, 640, 640);
        pe_edge_kernel<32, 1><<<EG / 32, 256, 0, stream>>>(
            gg_ef_bf, wt_fij1, gg_src, gg_dst, Pn1, attn_p1, esc, y22p, 0, EG, NG);
        csr_softmax_kernel<8><<<NG / 4, 256, 0, stream>>>(gg_row, gg_eidx, esc, wcsr, NG);
        u16* Pnode1 = slab;   // alias: Pn1 dead
        gemm_bf_kernel<64><<<dim3(NG / 64, 5), 256, 0, stream>>>(
            gg_nf_bf, wt_node1, b_node1, Pnode1, 320, 320);
        node_agg_kernel<40, 8, 0, 320><<<NG / 4, 256, 0, stream>>>(gg_row, gg_srcs, wcsr,
                                                                   Pnode1, y2n, NG);
    }

    // ef for lg layer 2a
    ef2a_kernel<<<cdiv(EL * 64, 256), 256, 0, stream>>>(lg_ef, y2n, ef_shared);

    // ---------------- stage 2 (lg), two layers ----------------
    for (int layer = 0; layer < 2; ++layer) {
        const bool a = (layer == 0);
        const u16* nf_in = a ? lg_nf_bf : nfa_bf;
        const u16* Wninj = a ? wt_ninj2a : wt_ninj2b;
        const u16* Wfij = a ? wt_fij2a : wt_fij2b;
        const u16* Wnode = a ? wt_node2a : wt_node2b;
        const float* bn = a ? b_node2a : b_node2b;
        const float* bcat = a ? bias_cat2a : bias_cat2b;
        const float* at = a ? attn2a : attn2b;
        u16* nf_out = a ? nfa_bf : nfb_bf;

        u16* Pn2 = slab;                                  // [NL][640]
        gemm_bf_kernel<96><<<dim3(NL / 64, 10), 256, 0, stream>>>(nf_in, Wninj, bcat, Pn2, 640, 640);
        if (a)
            pe_edge_kernel<64, 2><<<EL / 32, 256, 0, stream>>>(
                ef_shared, Wfij, lg_src, lg_dst, Pn2, at, esc, ef_shared, 0, EL, EL);
        else
            pe_edge_kernel<64, 0><<<EL / 32, 256, 0, stream>>>(
                ef_shared, Wfij, lg_src, lg_dst, Pn2, at, esc, nullptr, 0, EL, 0);
        csr_softmax_kernel<8><<<NL / 4, 256, 0, stream>>>(lg_row, lg_eidx, esc, wcsr, NL);
        u16* Pnode2 = slab;   // alias: Pn2 dead; stride 768 (row 1536B, 128B-aligned)
        gemm_bf_kernel<96><<<dim3(NL / 64, 12), 256, 0, stream>>>(nf_in, Wnode, bn, Pnode2, 736, 768);
        node_agg_kernel<92, 8, 1, 768><<<NL / 4, 256, 0, stream>>>(lg_row, lg_srcs, wcsr,
                                                                   Pnode2, nf_out, NL);
    }

    // ---------------- readout ----------------
    readout_kernel<<<NB, 256, 0, stream>>>(nfb_bf, y22p, Wr1, br1, Wr2, br2, out);
}